// Round 1
// baseline (3645.974 us; speedup 1.0000x reference)
//
#include <hip/hip_runtime.h>

static constexpr int Bsz = 512;
static constexpr int Tsz = 256;
static constexpr int Nsz = 128;
static constexpr int Msz = 256;

using short8 = __attribute__((ext_vector_type(8))) short;
using f32x4  = __attribute__((ext_vector_type(4))) float;

__device__ __forceinline__ float rcp_fast(float v){ return __builtin_amdgcn_rcpf(v); }
__device__ __forceinline__ float sigmoid_fast(float v){ return rcp_fast(1.0f + __expf(-v)); }
__device__ __forceinline__ float tanh_fast(float v){ return 1.0f - 2.0f * rcp_fast(1.0f + __expf(2.0f * v)); }
__device__ __forceinline__ unsigned short bf16r(float f){
  unsigned u = __float_as_uint(f);
  u += 0x7FFFu + ((u >> 16) & 1u);
  return (unsigned short)(u >> 16);
}

// ---------------------------------------------------------------------------
// K0: HS slab t=0 (bf16 h,s) + zero the scan barrier counters.
// HS layout: [t][b][j], j<256 -> h, j>=256 -> s (bf16, row stride 512)
// ctr: 255 steps x 32 batch groups = 8160 ints (zero 8192)
// ---------------------------------------------------------------------------
__global__ __launch_bounds__(256) void k_init(const float* __restrict__ h_in,
                                              const float* __restrict__ s_in,
                                              unsigned short* __restrict__ HS,
                                              int* __restrict__ ctr){
  const int i = blockIdx.x * 256 + threadIdx.x;   // 0 .. B*M-1 (131072)
  if (i < 8192) ctr[i] = 0;
  const float h = h_in[i];
  const float s = s_in[i];
  const int b = i >> 8;
  const int m = i & 255;
  unsigned short* row = HS + (size_t)b * 512;
  row[m]       = bf16r(h);
  row[256 + m] = bf16r(s);
}

// ---------------------------------------------------------------------------
// K1: Q[b][n][u] = exp( 2 * sum_t x[b][t][n] * Ue[t][u] )   (r2, pre-exp'd)
// ---------------------------------------------------------------------------
__global__ __launch_bounds__(256) void k_r2exp(const float* __restrict__ x,
                                               const float* __restrict__ Ue,
                                               float* __restrict__ Q){
  const int b  = blockIdx.x;
  const int n0 = (blockIdx.y >> 2) * 64;
  const int u0 = (blockIdx.y & 3) * 64;
  __shared__ float Al[16][68];
  __shared__ float Bl[16][68];
  const int tid  = threadIdx.x;
  const int lane = tid & 63;
  const int kq   = tid >> 6;
  const int ty   = tid >> 4;
  const int tx   = tid & 15;
  float acc[4][4] = {};
  const float* xb = x + (size_t)b * Tsz * Nsz;
  for (int k0 = 0; k0 < Tsz; k0 += 16){
    #pragma unroll
    for (int i = 0; i < 4; ++i){
      const int k = kq*4 + i;
      Al[k][lane] = xb[(size_t)(k0+k)*Nsz + n0 + lane];
      Bl[k][lane] = Ue[(size_t)(k0+k)*Tsz + u0 + lane];
    }
    __syncthreads();
    #pragma unroll
    for (int kk = 0; kk < 16; ++kk){
      const float4 a = *(const float4*)&Al[kk][ty*4];
      const float4 w = *(const float4*)&Bl[kk][tx*4];
      const float av[4] = {a.x,a.y,a.z,a.w};
      const float wv[4] = {w.x,w.y,w.z,w.w};
      #pragma unroll
      for (int i=0;i<4;++i)
        #pragma unroll
        for (int j=0;j<4;++j)
          acc[i][j] = fmaf(av[i], wv[j], acc[i][j]);
    }
    __syncthreads();
  }
  float* Qb = Q + (size_t)b * Nsz * Tsz;
  #pragma unroll
  for (int i=0;i<4;++i){
    float4 v;
    v.x = __expf(2.0f*acc[i][0]);
    v.y = __expf(2.0f*acc[i][1]);
    v.z = __expf(2.0f*acc[i][2]);
    v.w = __expf(2.0f*acc[i][3]);
    *(float4*)&Qb[(size_t)(n0 + ty*4 + i)*Tsz + u0 + tx*4] = v;
  }
}

// ---------------------------------------------------------------------------
// K2: persistent LSTM scan, v2.
// Grid 128 = 32 batch-groups (16 b) x 4 unit-groups (64 units -> 256 z cols).
//   bgq = blockIdx.x & 31  -> a group's 4 blocks are {bgq+32*ug}, all equal
//   mod 8 -> same XCD under round-robin dispatch (locality heuristic only).
// Per step: stage x_t + run x@Wk MFMAs BEFORE the group barrier (h-independent),
// then acquire-spin (4 participants), stage h_t, 32 h@Wr MFMAs, gates,
// write h/s bf16 to HS[t+1], release-add.
// Wave w owns unit subtile u0+16w..+16; per-lane: 4 batch rows x 1 unit x 4 gates.
// ---------------------------------------------------------------------------
__global__ __launch_bounds__(256, 1) void k_scan(const float* __restrict__ x,
                                                 const float* __restrict__ Wk,
                                                 const float* __restrict__ Wr,
                                                 const float* __restrict__ bias,
                                                 const float* __restrict__ s_in,
                                                 unsigned short* __restrict__ HS,
                                                 int* __restrict__ ctr){
  const int bgq = blockIdx.x & 31;    // batch group 0..31 (16 batches)
  const int ug  = blockIdx.x >> 5;    // unit group 0..3 (64 units)
  const int b0  = bgq * 16;
  const int u0  = ug * 64;
  const int tid  = threadIdx.x;
  const int w    = tid >> 6;          // wave 0..3 -> units u0+16w..
  const int lane = tid & 63;
  const int nl   = lane & 15;
  const int kq   = lane >> 4;

  __shared__ unsigned short Xa[4*16*32];   // x_t  chunks (k=0..127),   4 KB
  __shared__ unsigned short Ha[8*16*32];   // h_t  chunks (k=128..383), 8 KB

  const int ucol = u0 + (w<<4) + nl;       // this lane's unit column

  // ---- preload W fragments (bf16) into registers: 12 chunks x 4 gates ----
  short8 wf[12][4];
  #pragma unroll
  for (int c = 0; c < 12; ++c){
    #pragma unroll
    for (int g = 0; g < 4; ++g){
      const int jcol = g*Msz + ucol;
      short8 f;
      #pragma unroll
      for (int j = 0; j < 8; ++j){
        const int k = c*32 + kq*8 + j;
        const float wv = (k < Nsz) ? Wk[(size_t)k*(4*Msz) + jcol]
                                   : Wr[(size_t)(k - Nsz)*(4*Msz) + jcol];
        f[j] = (short)bf16r(wv);
      }
      wf[c][g] = f;
    }
  }

  // ---- per-lane state: 4 batch rows x 1 unit ----
  const int r0 = kq*4;                     // first of 4 batch rows (C layout)
  float bi[4];
  #pragma unroll
  for (int g = 0; g < 4; ++g) bi[g] = bias[g*Msz + ucol];
  float s_reg[4];
  #pragma unroll
  for (int r = 0; r < 4; ++r)
    s_reg[r] = s_in[(size_t)(b0 + r0 + r)*Msz + ucol];

  // staging indices (256 threads cover 16 rows x full width)
  const int srow = tid >> 4;               // 0..15
  const int sx_n = (tid & 15) * 8;         // x col base (8 fp32)
  const int sh_m = (tid & 15) * 16;        // h col base (16 bf16)
  const int arow = nl*32 + kq*8;           // A-fragment LDS offset (shorts)

  #pragma unroll 1
  for (int t = 0; t < Tsz - 1; ++t){
    // ---- stage x_t (no dependence on the group barrier) ----
    {
      const float* xp = x + ((size_t)(b0+srow)*Tsz + t)*Nsz + sx_n;
      const float4 v0 = *(const float4*)(xp);
      const float4 v1 = *(const float4*)(xp + 4);
      ushort4 o0, o1;
      o0.x = bf16r(v0.x); o0.y = bf16r(v0.y); o0.z = bf16r(v0.z); o0.w = bf16r(v0.w);
      o1.x = bf16r(v1.x); o1.y = bf16r(v1.y); o1.z = bf16r(v1.z); o1.w = bf16r(v1.w);
      const int base = (sx_n>>5)*512 + srow*32 + (sx_n & 31);
      *(ushort4*)&Xa[base]     = o0;
      *(ushort4*)&Xa[base + 4] = o1;
    }
    __syncthreads();   // Xa ready (WAR vs prior step covered by end-of-step barrier)

    // ---- x_t @ Wk : chunks 0..3 (overlaps producers still finishing h_t) ----
    f32x4 acc0 = {0.f,0.f,0.f,0.f}, acc1 = {0.f,0.f,0.f,0.f};
    f32x4 acc2 = {0.f,0.f,0.f,0.f}, acc3 = {0.f,0.f,0.f,0.f};
    #pragma unroll
    for (int c = 0; c < 4; ++c){
      const short8 af = *(const short8*)&Xa[c*512 + arow];
      acc0 = __builtin_amdgcn_mfma_f32_16x16x32_bf16(af, wf[c][0], acc0, 0, 0, 0);
      acc1 = __builtin_amdgcn_mfma_f32_16x16x32_bf16(af, wf[c][1], acc1, 0, 0, 0);
      acc2 = __builtin_amdgcn_mfma_f32_16x16x32_bf16(af, wf[c][2], acc2, 0, 0, 0);
      acc3 = __builtin_amdgcn_mfma_f32_16x16x32_bf16(af, wf[c][3], acc3, 0, 0, 0);
    }

    // ---- wait for h_t (4 producers; uniform spin, all lanes/waves) ----
    if (t > 0){
      int* cp = &ctr[(t-1)*32 + bgq];
      while (__hip_atomic_load(cp, __ATOMIC_ACQUIRE, __HIP_MEMORY_SCOPE_AGENT) < 4)
        __builtin_amdgcn_s_sleep(1);
    }

    // ---- stage h_t (bf16 copy): 16 rows x 256 m ----
    {
      const unsigned short* src = HS + ((size_t)t*Bsz + b0 + srow)*512 + sh_m;
      const uint4 va = *(const uint4*)(src);
      const uint4 vb = *(const uint4*)(src + 8);
      const int base = (sh_m>>5)*512 + srow*32 + (sh_m & 31);
      *(uint4*)&Ha[base]     = va;
      *(uint4*)&Ha[base + 8] = vb;
    }
    __syncthreads();   // Ha ready

    // ---- h_t @ Wr : chunks 4..11 ----
    #pragma unroll
    for (int c = 0; c < 8; ++c){
      const short8 af = *(const short8*)&Ha[c*512 + arow];
      acc0 = __builtin_amdgcn_mfma_f32_16x16x32_bf16(af, wf[c+4][0], acc0, 0, 0, 0);
      acc1 = __builtin_amdgcn_mfma_f32_16x16x32_bf16(af, wf[c+4][1], acc1, 0, 0, 0);
      acc2 = __builtin_amdgcn_mfma_f32_16x16x32_bf16(af, wf[c+4][2], acc2, 0, 0, 0);
      acc3 = __builtin_amdgcn_mfma_f32_16x16x32_bf16(af, wf[c+4][3], acc3, 0, 0, 0);
    }

    // ---- gate update (in-register; C layout: col=nl, row=kq*4+r) ----
    #pragma unroll
    for (int r = 0; r < 4; ++r){
      const float ig = sigmoid_fast(acc0[r] + bi[0]);
      const float fg = sigmoid_fast(acc1[r] + bi[1]);
      const float gg = tanh_fast  (acc2[r] + bi[2]);
      const float og = sigmoid_fast(acc3[r] + bi[3]);
      const float s1 = fmaf(fg, s_reg[r], ig * gg);
      s_reg[r] = s1;
      const float hn = og * tanh_fast(s1);
      unsigned short* rp = HS + ((size_t)(t+1)*Bsz + b0 + r0 + r)*512;
      rp[ucol]       = bf16r(hn);
      rp[256 + ucol] = bf16r(s1);
    }

    // ---- publish h_{t+1}: drain writes, then one release-add per block ----
    __syncthreads();
    if (tid == 0)
      __hip_atomic_fetch_add(&ctr[t*32 + bgq], 1, __ATOMIC_RELEASE,
                             __HIP_MEMORY_SCOPE_AGENT);
  }
}

// ---------------------------------------------------------------------------
// K3: attention. Per block (b, 16 t's): HS bf16 -> fp32 LDS; fused r1 GEMM +
// exp; e = -2*sum_u ve_u/(1+P*Q) (softmax-equivalent); softmax; out=alpha*x.
// ---------------------------------------------------------------------------
__global__ __launch_bounds__(256) void k_attn(const unsigned short* __restrict__ HS,
                                              const float* __restrict__ Q,
                                              const float* __restrict__ We,
                                              const float* __restrict__ ve,
                                              const float* __restrict__ x,
                                              float* __restrict__ out){
  const int b  = blockIdx.x;
  const int t0 = blockIdx.y * 16;
  __shared__ float HSl[16][512];
  __shared__ float Pl[16][260];
  __shared__ float Ql[16][260];
  __shared__ float vel[256];
  __shared__ float El[16][128];
  __shared__ float red[16][16];
  __shared__ float rowm[16];
  __shared__ float rowsum[16];
  const int tid = threadIdx.x;
  vel[tid] = ve[tid];
  {
    const int row = tid >> 4;
    const int c0  = (tid & 15) * 32;
    const unsigned short* src = HS + ((size_t)(t0 + row) * Bsz + b) * 512 + c0;
    #pragma unroll
    for (int q = 0; q < 4; ++q){
      const uint4 v = *(const uint4*)(src + q * 8);
      const unsigned wv[4] = {v.x, v.y, v.z, v.w};
      #pragma unroll
      for (int e = 0; e < 4; ++e){
        HSl[row][c0 + q*8 + e*2 + 0] = __uint_as_float(wv[e] << 16);
        HSl[row][c0 + q*8 + e*2 + 1] = __uint_as_float(wv[e] & 0xFFFF0000u);
      }
    }
  }
  __syncthreads();
  {
    const int lane = tid & 63;
    const int w    = tid >> 6;
    float acc[4][4] = {};
    for (int k = 0; k < 2*Msz; k += 4){
      float a[4][4];
      #pragma unroll
      for (int ri = 0; ri < 4; ++ri){
        const float4 t4 = *(const float4*)&HSl[w + 4*ri][k];
        a[ri][0]=t4.x; a[ri][1]=t4.y; a[ri][2]=t4.z; a[ri][3]=t4.w;
      }
      #pragma unroll
      for (int kk = 0; kk < 4; ++kk){
        const float4 wv = *(const float4*)(We + (size_t)(k+kk) * Tsz + lane*4);
        const float wa[4] = {wv.x, wv.y, wv.z, wv.w};
        #pragma unroll
        for (int ri=0; ri<4; ++ri)
          #pragma unroll
          for (int j=0;j<4;++j)
            acc[ri][j] = fmaf(a[ri][kk], wa[j], acc[ri][j]);
      }
    }
    #pragma unroll
    for (int ri = 0; ri < 4; ++ri)
      #pragma unroll
      for (int j = 0; j < 4; ++j)
        Pl[w + 4*ri][lane*4 + j] = __expf(2.0f * acc[ri][j]);
  }
  const int t  = tid >> 4;
  const int nl = tid & 15;
  for (int n0 = 0; n0 < Nsz; n0 += 16){
    __syncthreads();
    {
      const int row = tid >> 4;
      const int uc  = (tid & 15) * 16;
      const float* src = Q + ((size_t)b * Nsz + n0 + row) * Tsz + uc;
      #pragma unroll
      for (int i = 0; i < 4; ++i)
        *(float4*)&Ql[row][uc + i*4] = *(const float4*)&src[i*4];
    }
    __syncthreads();
    float acc = 0.0f;
    #pragma unroll 8
    for (int u = 0; u < Tsz; u += 4){
      const float4 p4 = *(const float4*)&Pl[t][u];
      const float4 q4 = *(const float4*)&Ql[nl][u];
      const float4 v4 = *(const float4*)&vel[u];
      acc = fmaf(v4.x, rcp_fast(fmaf(p4.x, q4.x, 1.0f)), acc);
      acc = fmaf(v4.y, rcp_fast(fmaf(p4.y, q4.y, 1.0f)), acc);
      acc = fmaf(v4.z, rcp_fast(fmaf(p4.z, q4.z, 1.0f)), acc);
      acc = fmaf(v4.w, rcp_fast(fmaf(p4.w, q4.w, 1.0f)), acc);
    }
    El[t][n0 + nl] = -2.0f * acc;
  }
  __syncthreads();
  const int j = nl;
  float mx = -3.0e38f;
  #pragma unroll
  for (int q=0;q<8;++q) mx = fmaxf(mx, El[t][j*8+q]);
  red[t][j] = mx;
  __syncthreads();
  if (j == 0){
    float m2 = red[t][0];
    #pragma unroll
    for (int q=1;q<16;++q) m2 = fmaxf(m2, red[t][q]);
    rowm[t] = m2;
  }
  __syncthreads();
  const float rm = rowm[t];
  float sm = 0.0f;
  #pragma unroll
  for (int q=0;q<8;++q){
    const float p = __expf(El[t][j*8+q] - rm);
    El[t][j*8+q] = p;
    sm += p;
  }
  red[t][j] = sm;
  __syncthreads();
  if (j == 0){
    float s2 = 0.0f;
    #pragma unroll
    for (int q=0;q<16;++q) s2 += red[t][q];
    rowsum[t] = s2;
  }
  __syncthreads();
  const float inv = rcp_fast(rowsum[t]);
  const float* xr   = x   + ((size_t)b*Tsz + t0 + t)*Nsz + j*8;
  float*       orow = out + ((size_t)b*Tsz + t0 + t)*Nsz + j*8;
  #pragma unroll
  for (int q=0;q<8;++q)
    orow[q] = El[t][j*8+q] * inv * xr[q];
}

// ---------------------------------------------------------------------------
extern "C" void kernel_launch(void* const* d_in, const int* in_sizes, int n_in,
                              void* d_out, int out_size, void* d_ws, size_t ws_size,
                              hipStream_t stream){
  const float* x    = (const float*)d_in[0];
  const float* s_in = (const float*)d_in[1];
  const float* h_in = (const float*)d_in[2];
  const float* We   = (const float*)d_in[3];
  const float* Ue   = (const float*)d_in[4];
  const float* ve   = (const float*)d_in[5];
  const float* Wk   = (const float*)d_in[6];
  const float* Wr   = (const float*)d_in[7];
  const float* bias = (const float*)d_in[8];
  float* out = (float*)d_out;

  // ws layout (~201.4 MB): Q fp32 67MB | HS bf16 134MB | ctr 32KB
  float* Q = (float*)d_ws;
  unsigned short* HS = (unsigned short*)(Q + (size_t)Bsz*Nsz*Tsz);
  int* ctr = (int*)(HS + (size_t)Tsz*Bsz*512);

  k_init<<<(Bsz*Msz)/256, 256, 0, stream>>>(h_in, s_in, HS, ctr);
  k_r2exp<<<dim3(Bsz, 8), 256, 0, stream>>>(x, Ue, Q);
  k_scan<<<128, 256, 0, stream>>>(x, Wk, Wr, bias, s_in, HS, ctr);
  k_attn<<<dim3(Bsz, Tsz/16), 256, 0, stream>>>(HS, Q, We, ve, x, out);
}

// Round 2
// 2639.811 us; speedup vs baseline: 1.3811x; 1.3811x over previous
//
#include <hip/hip_runtime.h>

static constexpr int Bsz = 512;
static constexpr int Tsz = 256;
static constexpr int Nsz = 128;
static constexpr int Msz = 256;

using short8 = __attribute__((ext_vector_type(8))) short;
using f32x4  = __attribute__((ext_vector_type(4))) float;

__device__ __forceinline__ float rcp_fast(float v){ return __builtin_amdgcn_rcpf(v); }
__device__ __forceinline__ float sigmoid_fast(float v){ return rcp_fast(1.0f + __expf(-v)); }
__device__ __forceinline__ float tanh_fast(float v){ return 1.0f - 2.0f * rcp_fast(1.0f + __expf(2.0f * v)); }
__device__ __forceinline__ unsigned short bf16r(float f){
  unsigned u = __float_as_uint(f);
  u += 0x7FFFu + ((u >> 16) & 1u);
  return (unsigned short)(u >> 16);
}

// ---------------------------------------------------------------------------
// K0: HS slab t=0 (bf16 h,s) + zero the scan barrier counters.
// HS layout: [t][b][j], j<256 -> h, j>=256 -> s (bf16, row stride 512)
// ctr: 255 steps x 32 batch groups = 8160 ints (zero 8192)
// ---------------------------------------------------------------------------
__global__ __launch_bounds__(256) void k_init(const float* __restrict__ h_in,
                                              const float* __restrict__ s_in,
                                              unsigned short* __restrict__ HS,
                                              int* __restrict__ ctr){
  const int i = blockIdx.x * 256 + threadIdx.x;   // 0 .. B*M-1 (131072)
  if (i < 8192) ctr[i] = 0;
  const float h = h_in[i];
  const float s = s_in[i];
  const int b = i >> 8;
  const int m = i & 255;
  unsigned short* row = HS + (size_t)b * 512;
  row[m]       = bf16r(h);
  row[256 + m] = bf16r(s);
}

// ---------------------------------------------------------------------------
// K1: Q[b][n][u] = exp( 2 * sum_t x[b][t][n] * Ue[t][u] )   (r2, pre-exp'd)
// ---------------------------------------------------------------------------
__global__ __launch_bounds__(256) void k_r2exp(const float* __restrict__ x,
                                               const float* __restrict__ Ue,
                                               float* __restrict__ Q){
  const int b  = blockIdx.x;
  const int n0 = (blockIdx.y >> 2) * 64;
  const int u0 = (blockIdx.y & 3) * 64;
  __shared__ float Al[16][68];
  __shared__ float Bl[16][68];
  const int tid  = threadIdx.x;
  const int lane = tid & 63;
  const int kq   = tid >> 6;
  const int ty   = tid >> 4;
  const int tx   = tid & 15;
  float acc[4][4] = {};
  const float* xb = x + (size_t)b * Tsz * Nsz;
  for (int k0 = 0; k0 < Tsz; k0 += 16){
    #pragma unroll
    for (int i = 0; i < 4; ++i){
      const int k = kq*4 + i;
      Al[k][lane] = xb[(size_t)(k0+k)*Nsz + n0 + lane];
      Bl[k][lane] = Ue[(size_t)(k0+k)*Tsz + u0 + lane];
    }
    __syncthreads();
    #pragma unroll
    for (int kk = 0; kk < 16; ++kk){
      const float4 a = *(const float4*)&Al[kk][ty*4];
      const float4 w = *(const float4*)&Bl[kk][tx*4];
      const float av[4] = {a.x,a.y,a.z,a.w};
      const float wv[4] = {w.x,w.y,w.z,w.w};
      #pragma unroll
      for (int i=0;i<4;++i)
        #pragma unroll
        for (int j=0;j<4;++j)
          acc[i][j] = fmaf(av[i], wv[j], acc[i][j]);
    }
    __syncthreads();
  }
  float* Qb = Q + (size_t)b * Nsz * Tsz;
  #pragma unroll
  for (int i=0;i<4;++i){
    float4 v;
    v.x = __expf(2.0f*acc[i][0]);
    v.y = __expf(2.0f*acc[i][1]);
    v.z = __expf(2.0f*acc[i][2]);
    v.w = __expf(2.0f*acc[i][3]);
    *(float4*)&Qb[(size_t)(n0 + ty*4 + i)*Tsz + u0 + tx*4] = v;
  }
}

// ---------------------------------------------------------------------------
// K2: persistent LSTM scan, v3 (sync-protocol fix).
// Grid 128 = 32 batch-groups (16 b) x 4 unit-groups (64 units -> 256 z cols).
// Per step: stage x_t + x@Wk MFMAs BEFORE the wait (h-independent); then
// tid0-only RELAXED spin (sc1 coherent load, NO per-poll L2 invalidate),
// ONE acquire load (single buffer_inv) after the spin; stage h_t; h@Wr;
// gates; HS[t+1] bf16 write; syncthreads; single release fetch_add (one wbl2).
// ---------------------------------------------------------------------------
__global__ __launch_bounds__(256, 1) void k_scan(const float* __restrict__ x,
                                                 const float* __restrict__ Wk,
                                                 const float* __restrict__ Wr,
                                                 const float* __restrict__ bias,
                                                 const float* __restrict__ s_in,
                                                 unsigned short* __restrict__ HS,
                                                 int* __restrict__ ctr){
  const int bgq = blockIdx.x & 31;    // batch group 0..31 (16 batches)
  const int ug  = blockIdx.x >> 5;    // unit group 0..3 (64 units)
  const int b0  = bgq * 16;
  const int u0  = ug * 64;
  const int tid  = threadIdx.x;
  const int w    = tid >> 6;          // wave 0..3 -> units u0+16w..
  const int lane = tid & 63;
  const int nl   = lane & 15;
  const int kq   = lane >> 4;

  __shared__ unsigned short Xa[4*16*32];   // x_t  chunks (k=0..127),   4 KB
  __shared__ unsigned short Ha[8*16*32];   // h_t  chunks (k=128..383), 8 KB

  const int ucol = u0 + (w<<4) + nl;       // this lane's unit column

  // ---- preload W fragments (bf16) into registers: 12 chunks x 4 gates ----
  short8 wf[12][4];
  #pragma unroll
  for (int c = 0; c < 12; ++c){
    #pragma unroll
    for (int g = 0; g < 4; ++g){
      const int jcol = g*Msz + ucol;
      short8 f;
      #pragma unroll
      for (int j = 0; j < 8; ++j){
        const int k = c*32 + kq*8 + j;
        const float wv = (k < Nsz) ? Wk[(size_t)k*(4*Msz) + jcol]
                                   : Wr[(size_t)(k - Nsz)*(4*Msz) + jcol];
        f[j] = (short)bf16r(wv);
      }
      wf[c][g] = f;
    }
  }

  // ---- per-lane state: 4 batch rows x 1 unit ----
  const int r0 = kq*4;                     // first of 4 batch rows (C layout)
  float bi[4];
  #pragma unroll
  for (int g = 0; g < 4; ++g) bi[g] = bias[g*Msz + ucol];
  float s_reg[4];
  #pragma unroll
  for (int r = 0; r < 4; ++r)
    s_reg[r] = s_in[(size_t)(b0 + r0 + r)*Msz + ucol];

  // staging indices (256 threads cover 16 rows x full width)
  const int srow = tid >> 4;               // 0..15
  const int sx_n = (tid & 15) * 8;         // x col base (8 fp32)
  const int sh_m = (tid & 15) * 16;        // h col base (16 bf16)
  const int arow = nl*32 + kq*8;           // A-fragment LDS offset (shorts)

  #pragma unroll 1
  for (int t = 0; t < Tsz - 1; ++t){
    // ---- stage x_t (no dependence on the group barrier) ----
    {
      const float* xp = x + ((size_t)(b0+srow)*Tsz + t)*Nsz + sx_n;
      const float4 v0 = *(const float4*)(xp);
      const float4 v1 = *(const float4*)(xp + 4);
      ushort4 o0, o1;
      o0.x = bf16r(v0.x); o0.y = bf16r(v0.y); o0.z = bf16r(v0.z); o0.w = bf16r(v0.w);
      o1.x = bf16r(v1.x); o1.y = bf16r(v1.y); o1.z = bf16r(v1.z); o1.w = bf16r(v1.w);
      const int base = (sx_n>>5)*512 + srow*32 + (sx_n & 31);
      *(ushort4*)&Xa[base]     = o0;
      *(ushort4*)&Xa[base + 4] = o1;
    }
    __syncthreads();   // Xa ready (WAR vs prior step covered by later barriers)

    // ---- x_t @ Wk : chunks 0..3 (overlaps producers still finishing h_t) ----
    f32x4 acc0 = {0.f,0.f,0.f,0.f}, acc1 = {0.f,0.f,0.f,0.f};
    f32x4 acc2 = {0.f,0.f,0.f,0.f}, acc3 = {0.f,0.f,0.f,0.f};
    #pragma unroll
    for (int c = 0; c < 4; ++c){
      const short8 af = *(const short8*)&Xa[c*512 + arow];
      acc0 = __builtin_amdgcn_mfma_f32_16x16x32_bf16(af, wf[c][0], acc0, 0, 0, 0);
      acc1 = __builtin_amdgcn_mfma_f32_16x16x32_bf16(af, wf[c][1], acc1, 0, 0, 0);
      acc2 = __builtin_amdgcn_mfma_f32_16x16x32_bf16(af, wf[c][2], acc2, 0, 0, 0);
      acc3 = __builtin_amdgcn_mfma_f32_16x16x32_bf16(af, wf[c][3], acc3, 0, 0, 0);
    }

    // ---- wait for h_t: tid0 relaxed spin (sc1, no inv), then ONE acquire ----
    if (t > 0){
      if (tid == 0){
        int* cp = &ctr[(t-1)*32 + bgq];
        while (__hip_atomic_load(cp, __ATOMIC_RELAXED, __HIP_MEMORY_SCOPE_AGENT) < 4)
          __builtin_amdgcn_s_sleep(2);
        // single L2 invalidate per block per step, AFTER the flag is seen
        (void)__hip_atomic_load(cp, __ATOMIC_ACQUIRE, __HIP_MEMORY_SCOPE_AGENT);
      }
      __syncthreads();   // all waves' h-loads ordered after the invalidate
    }

    // ---- stage h_t (bf16 copy): 16 rows x 256 m ----
    {
      const unsigned short* src = HS + ((size_t)t*Bsz + b0 + srow)*512 + sh_m;
      const uint4 va = *(const uint4*)(src);
      const uint4 vb = *(const uint4*)(src + 8);
      const int base = (sh_m>>5)*512 + srow*32 + (sh_m & 31);
      *(uint4*)&Ha[base]     = va;
      *(uint4*)&Ha[base + 8] = vb;
    }
    __syncthreads();   // Ha ready

    // ---- h_t @ Wr : chunks 4..11 ----
    #pragma unroll
    for (int c = 0; c < 8; ++c){
      const short8 af = *(const short8*)&Ha[c*512 + arow];
      acc0 = __builtin_amdgcn_mfma_f32_16x16x32_bf16(af, wf[c+4][0], acc0, 0, 0, 0);
      acc1 = __builtin_amdgcn_mfma_f32_16x16x32_bf16(af, wf[c+4][1], acc1, 0, 0, 0);
      acc2 = __builtin_amdgcn_mfma_f32_16x16x32_bf16(af, wf[c+4][2], acc2, 0, 0, 0);
      acc3 = __builtin_amdgcn_mfma_f32_16x16x32_bf16(af, wf[c+4][3], acc3, 0, 0, 0);
    }

    // ---- gate update (in-register; C layout: col=nl, row=kq*4+r) ----
    #pragma unroll
    for (int r = 0; r < 4; ++r){
      const float ig = sigmoid_fast(acc0[r] + bi[0]);
      const float fg = sigmoid_fast(acc1[r] + bi[1]);
      const float gg = tanh_fast  (acc2[r] + bi[2]);
      const float og = sigmoid_fast(acc3[r] + bi[3]);
      const float s1 = fmaf(fg, s_reg[r], ig * gg);
      s_reg[r] = s1;
      const float hn = og * tanh_fast(s1);
      unsigned short* rp = HS + ((size_t)(t+1)*Bsz + b0 + r0 + r)*512;
      rp[ucol]       = bf16r(hn);
      rp[256 + ucol] = bf16r(s1);
    }

    // ---- publish h_{t+1}: drain writes, then one release-add per block ----
    __syncthreads();
    if (tid == 0)
      __hip_atomic_fetch_add(&ctr[t*32 + bgq], 1, __ATOMIC_RELEASE,
                             __HIP_MEMORY_SCOPE_AGENT);
  }
}

// ---------------------------------------------------------------------------
// K3: attention. Per block (b, 16 t's): HS bf16 -> fp32 LDS; fused r1 GEMM +
// exp; e = -2*sum_u ve_u/(1+P*Q) (softmax-equivalent); softmax; out=alpha*x.
// ---------------------------------------------------------------------------
__global__ __launch_bounds__(256) void k_attn(const unsigned short* __restrict__ HS,
                                              const float* __restrict__ Q,
                                              const float* __restrict__ We,
                                              const float* __restrict__ ve,
                                              const float* __restrict__ x,
                                              float* __restrict__ out){
  const int b  = blockIdx.x;
  const int t0 = blockIdx.y * 16;
  __shared__ float HSl[16][512];
  __shared__ float Pl[16][260];
  __shared__ float Ql[16][260];
  __shared__ float vel[256];
  __shared__ float El[16][128];
  __shared__ float red[16][16];
  __shared__ float rowm[16];
  __shared__ float rowsum[16];
  const int tid = threadIdx.x;
  vel[tid] = ve[tid];
  {
    const int row = tid >> 4;
    const int c0  = (tid & 15) * 32;
    const unsigned short* src = HS + ((size_t)(t0 + row) * Bsz + b) * 512 + c0;
    #pragma unroll
    for (int q = 0; q < 4; ++q){
      const uint4 v = *(const uint4*)(src + q * 8);
      const unsigned wv[4] = {v.x, v.y, v.z, v.w};
      #pragma unroll
      for (int e = 0; e < 4; ++e){
        HSl[row][c0 + q*8 + e*2 + 0] = __uint_as_float(wv[e] << 16);
        HSl[row][c0 + q*8 + e*2 + 1] = __uint_as_float(wv[e] & 0xFFFF0000u);
      }
    }
  }
  __syncthreads();
  {
    const int lane = tid & 63;
    const int w    = tid >> 6;
    float acc[4][4] = {};
    for (int k = 0; k < 2*Msz; k += 4){
      float a[4][4];
      #pragma unroll
      for (int ri = 0; ri < 4; ++ri){
        const float4 t4 = *(const float4*)&HSl[w + 4*ri][k];
        a[ri][0]=t4.x; a[ri][1]=t4.y; a[ri][2]=t4.z; a[ri][3]=t4.w;
      }
      #pragma unroll
      for (int kk = 0; kk < 4; ++kk){
        const float4 wv = *(const float4*)(We + (size_t)(k+kk) * Tsz + lane*4);
        const float wa[4] = {wv.x, wv.y, wv.z, wv.w};
        #pragma unroll
        for (int ri=0; ri<4; ++ri)
          #pragma unroll
          for (int j=0;j<4;++j)
            acc[ri][j] = fmaf(a[ri][kk], wa[j], acc[ri][j]);
      }
    }
    #pragma unroll
    for (int ri = 0; ri < 4; ++ri)
      #pragma unroll
      for (int j = 0; j < 4; ++j)
        Pl[w + 4*ri][lane*4 + j] = __expf(2.0f * acc[ri][j]);
  }
  const int t  = tid >> 4;
  const int nl = tid & 15;
  for (int n0 = 0; n0 < Nsz; n0 += 16){
    __syncthreads();
    {
      const int row = tid >> 4;
      const int uc  = (tid & 15) * 16;
      const float* src = Q + ((size_t)b * Nsz + n0 + row) * Tsz + uc;
      #pragma unroll
      for (int i = 0; i < 4; ++i)
        *(float4*)&Ql[row][uc + i*4] = *(const float4*)&src[i*4];
    }
    __syncthreads();
    float acc = 0.0f;
    #pragma unroll 8
    for (int u = 0; u < Tsz; u += 4){
      const float4 p4 = *(const float4*)&Pl[t][u];
      const float4 q4 = *(const float4*)&Ql[nl][u];
      const float4 v4 = *(const float4*)&vel[u];
      acc = fmaf(v4.x, rcp_fast(fmaf(p4.x, q4.x, 1.0f)), acc);
      acc = fmaf(v4.y, rcp_fast(fmaf(p4.y, q4.y, 1.0f)), acc);
      acc = fmaf(v4.z, rcp_fast(fmaf(p4.z, q4.z, 1.0f)), acc);
      acc = fmaf(v4.w, rcp_fast(fmaf(p4.w, q4.w, 1.0f)), acc);
    }
    El[t][n0 + nl] = -2.0f * acc;
  }
  __syncthreads();
  const int j = nl;
  float mx = -3.0e38f;
  #pragma unroll
  for (int q=0;q<8;++q) mx = fmaxf(mx, El[t][j*8+q]);
  red[t][j] = mx;
  __syncthreads();
  if (j == 0){
    float m2 = red[t][0];
    #pragma unroll
    for (int q=1;q<16;++q) m2 = fmaxf(m2, red[t][q]);
    rowm[t] = m2;
  }
  __syncthreads();
  const float rm = rowm[t];
  float sm = 0.0f;
  #pragma unroll
  for (int q=0;q<8;++q){
    const float p = __expf(El[t][j*8+q] - rm);
    El[t][j*8+q] = p;
    sm += p;
  }
  red[t][j] = sm;
  __syncthreads();
  if (j == 0){
    float s2 = 0.0f;
    #pragma unroll
    for (int q=0;q<16;++q) s2 += red[t][q];
    rowsum[t] = s2;
  }
  __syncthreads();
  const float inv = rcp_fast(rowsum[t]);
  const float* xr   = x   + ((size_t)b*Tsz + t0 + t)*Nsz + j*8;
  float*       orow = out + ((size_t)b*Tsz + t0 + t)*Nsz + j*8;
  #pragma unroll
  for (int q=0;q<8;++q)
    orow[q] = El[t][j*8+q] * inv * xr[q];
}

// ---------------------------------------------------------------------------
extern "C" void kernel_launch(void* const* d_in, const int* in_sizes, int n_in,
                              void* d_out, int out_size, void* d_ws, size_t ws_size,
                              hipStream_t stream){
  const float* x    = (const float*)d_in[0];
  const float* s_in = (const float*)d_in[1];
  const float* h_in = (const float*)d_in[2];
  const float* We   = (const float*)d_in[3];
  const float* Ue   = (const float*)d_in[4];
  const float* ve   = (const float*)d_in[5];
  const float* Wk   = (const float*)d_in[6];
  const float* Wr   = (const float*)d_in[7];
  const float* bias = (const float*)d_in[8];
  float* out = (float*)d_out;

  // ws layout (~201.4 MB): Q fp32 67MB | HS bf16 134MB | ctr 32KB
  float* Q = (float*)d_ws;
  unsigned short* HS = (unsigned short*)(Q + (size_t)Bsz*Nsz*Tsz);
  int* ctr = (int*)(HS + (size_t)Tsz*Bsz*512);

  k_init<<<(Bsz*Msz)/256, 256, 0, stream>>>(h_in, s_in, HS, ctr);
  k_r2exp<<<dim3(Bsz, 8), 256, 0, stream>>>(x, Ue, Q);
  k_scan<<<128, 256, 0, stream>>>(x, Wk, Wr, bias, s_in, HS, ctr);
  k_attn<<<dim3(Bsz, Tsz/16), 256, 0, stream>>>(HS, Q, We, ve, x, out);
}

// Round 3
// 2397.117 us; speedup vs baseline: 1.5210x; 1.1012x over previous
//
#include <hip/hip_runtime.h>

static constexpr int Bsz = 512;
static constexpr int Tsz = 256;
static constexpr int Nsz = 128;
static constexpr int Msz = 256;

using short8 = __attribute__((ext_vector_type(8))) short;
using f32x4  = __attribute__((ext_vector_type(4))) float;

__device__ __forceinline__ float rcp_fast(float v){ return __builtin_amdgcn_rcpf(v); }
__device__ __forceinline__ float sigmoid_fast(float v){ return rcp_fast(1.0f + __expf(-v)); }
__device__ __forceinline__ float tanh_fast(float v){ return 1.0f - 2.0f * rcp_fast(1.0f + __expf(2.0f * v)); }
__device__ __forceinline__ unsigned short bf16r(float f){
  unsigned u = __float_as_uint(f);
  u += 0x7FFFu + ((u >> 16) & 1u);
  return (unsigned short)(u >> 16);
}

// ---------------------------------------------------------------------------
// K0: HS slab t=0 (bf16 h,s) + zero the scan barrier counters.
// HS layout: [t][b][j], j<256 -> h, j>=256 -> s (bf16, row stride 512)
// ---------------------------------------------------------------------------
__global__ __launch_bounds__(256) void k_init(const float* __restrict__ h_in,
                                              const float* __restrict__ s_in,
                                              unsigned short* __restrict__ HS,
                                              int* __restrict__ ctr){
  const int i = blockIdx.x * 256 + threadIdx.x;   // 0 .. B*M-1 (131072)
  if (i < 8192) ctr[i] = 0;
  const float h = h_in[i];
  const float s = s_in[i];
  const int b = i >> 8;
  const int m = i & 255;
  unsigned short* row = HS + (size_t)b * 512;
  row[m]       = bf16r(h);
  row[256 + m] = bf16r(s);
}

// ---------------------------------------------------------------------------
// K1: Q[b][n][u] = exp( 2 * sum_t x[b][t][n] * Ue[t][u] )   (r2, pre-exp'd)
// ---------------------------------------------------------------------------
__global__ __launch_bounds__(256) void k_r2exp(const float* __restrict__ x,
                                               const float* __restrict__ Ue,
                                               float* __restrict__ Q){
  const int b  = blockIdx.x;
  const int n0 = (blockIdx.y >> 2) * 64;
  const int u0 = (blockIdx.y & 3) * 64;
  __shared__ float Al[16][68];
  __shared__ float Bl[16][68];
  const int tid  = threadIdx.x;
  const int lane = tid & 63;
  const int kq   = tid >> 6;
  const int ty   = tid >> 4;
  const int tx   = tid & 15;
  float acc[4][4] = {};
  const float* xb = x + (size_t)b * Tsz * Nsz;
  for (int k0 = 0; k0 < Tsz; k0 += 16){
    #pragma unroll
    for (int i = 0; i < 4; ++i){
      const int k = kq*4 + i;
      Al[k][lane] = xb[(size_t)(k0+k)*Nsz + n0 + lane];
      Bl[k][lane] = Ue[(size_t)(k0+k)*Tsz + u0 + lane];
    }
    __syncthreads();
    #pragma unroll
    for (int kk = 0; kk < 16; ++kk){
      const float4 a = *(const float4*)&Al[kk][ty*4];
      const float4 w = *(const float4*)&Bl[kk][tx*4];
      const float av[4] = {a.x,a.y,a.z,a.w};
      const float wv[4] = {w.x,w.y,w.z,w.w};
      #pragma unroll
      for (int i=0;i<4;++i)
        #pragma unroll
        for (int j=0;j<4;++j)
          acc[i][j] = fmaf(av[i], wv[j], acc[i][j]);
    }
    __syncthreads();
  }
  float* Qb = Q + (size_t)b * Nsz * Tsz;
  #pragma unroll
  for (int i=0;i<4;++i){
    float4 v;
    v.x = __expf(2.0f*acc[i][0]);
    v.y = __expf(2.0f*acc[i][1]);
    v.z = __expf(2.0f*acc[i][2]);
    v.w = __expf(2.0f*acc[i][3]);
    *(float4*)&Qb[(size_t)(n0 + ty*4 + i)*Tsz + u0 + tx*4] = v;
  }
}

// ---------------------------------------------------------------------------
// K2: persistent LSTM scan, v3 (unchanged from round 2 — sync-protocol fix).
// ---------------------------------------------------------------------------
__global__ __launch_bounds__(256, 1) void k_scan(const float* __restrict__ x,
                                                 const float* __restrict__ Wk,
                                                 const float* __restrict__ Wr,
                                                 const float* __restrict__ bias,
                                                 const float* __restrict__ s_in,
                                                 unsigned short* __restrict__ HS,
                                                 int* __restrict__ ctr){
  const int bgq = blockIdx.x & 31;    // batch group 0..31 (16 batches)
  const int ug  = blockIdx.x >> 5;    // unit group 0..3 (64 units)
  const int b0  = bgq * 16;
  const int u0  = ug * 64;
  const int tid  = threadIdx.x;
  const int w    = tid >> 6;          // wave 0..3 -> units u0+16w..
  const int lane = tid & 63;
  const int nl   = lane & 15;
  const int kq   = lane >> 4;

  __shared__ unsigned short Xa[4*16*32];   // x_t  chunks (k=0..127),   4 KB
  __shared__ unsigned short Ha[8*16*32];   // h_t  chunks (k=128..383), 8 KB

  const int ucol = u0 + (w<<4) + nl;       // this lane's unit column

  // ---- preload W fragments (bf16) into registers: 12 chunks x 4 gates ----
  short8 wf[12][4];
  #pragma unroll
  for (int c = 0; c < 12; ++c){
    #pragma unroll
    for (int g = 0; g < 4; ++g){
      const int jcol = g*Msz + ucol;
      short8 f;
      #pragma unroll
      for (int j = 0; j < 8; ++j){
        const int k = c*32 + kq*8 + j;
        const float wv = (k < Nsz) ? Wk[(size_t)k*(4*Msz) + jcol]
                                   : Wr[(size_t)(k - Nsz)*(4*Msz) + jcol];
        f[j] = (short)bf16r(wv);
      }
      wf[c][g] = f;
    }
  }

  // ---- per-lane state: 4 batch rows x 1 unit ----
  const int r0 = kq*4;                     // first of 4 batch rows (C layout)
  float bi[4];
  #pragma unroll
  for (int g = 0; g < 4; ++g) bi[g] = bias[g*Msz + ucol];
  float s_reg[4];
  #pragma unroll
  for (int r = 0; r < 4; ++r)
    s_reg[r] = s_in[(size_t)(b0 + r0 + r)*Msz + ucol];

  // staging indices (256 threads cover 16 rows x full width)
  const int srow = tid >> 4;               // 0..15
  const int sx_n = (tid & 15) * 8;         // x col base (8 fp32)
  const int sh_m = (tid & 15) * 16;        // h col base (16 bf16)
  const int arow = nl*32 + kq*8;           // A-fragment LDS offset (shorts)

  #pragma unroll 1
  for (int t = 0; t < Tsz - 1; ++t){
    // ---- stage x_t (no dependence on the group barrier) ----
    {
      const float* xp = x + ((size_t)(b0+srow)*Tsz + t)*Nsz + sx_n;
      const float4 v0 = *(const float4*)(xp);
      const float4 v1 = *(const float4*)(xp + 4);
      ushort4 o0, o1;
      o0.x = bf16r(v0.x); o0.y = bf16r(v0.y); o0.z = bf16r(v0.z); o0.w = bf16r(v0.w);
      o1.x = bf16r(v1.x); o1.y = bf16r(v1.y); o1.z = bf16r(v1.z); o1.w = bf16r(v1.w);
      const int base = (sx_n>>5)*512 + srow*32 + (sx_n & 31);
      *(ushort4*)&Xa[base]     = o0;
      *(ushort4*)&Xa[base + 4] = o1;
    }
    __syncthreads();   // Xa ready (WAR vs prior step covered by later barriers)

    // ---- x_t @ Wk : chunks 0..3 (overlaps producers still finishing h_t) ----
    f32x4 acc0 = {0.f,0.f,0.f,0.f}, acc1 = {0.f,0.f,0.f,0.f};
    f32x4 acc2 = {0.f,0.f,0.f,0.f}, acc3 = {0.f,0.f,0.f,0.f};
    #pragma unroll
    for (int c = 0; c < 4; ++c){
      const short8 af = *(const short8*)&Xa[c*512 + arow];
      acc0 = __builtin_amdgcn_mfma_f32_16x16x32_bf16(af, wf[c][0], acc0, 0, 0, 0);
      acc1 = __builtin_amdgcn_mfma_f32_16x16x32_bf16(af, wf[c][1], acc1, 0, 0, 0);
      acc2 = __builtin_amdgcn_mfma_f32_16x16x32_bf16(af, wf[c][2], acc2, 0, 0, 0);
      acc3 = __builtin_amdgcn_mfma_f32_16x16x32_bf16(af, wf[c][3], acc3, 0, 0, 0);
    }

    // ---- wait for h_t: tid0 relaxed spin (sc1, no inv), then ONE acquire ----
    if (t > 0){
      if (tid == 0){
        int* cp = &ctr[(t-1)*32 + bgq];
        while (__hip_atomic_load(cp, __ATOMIC_RELAXED, __HIP_MEMORY_SCOPE_AGENT) < 4)
          __builtin_amdgcn_s_sleep(2);
        // single L2 invalidate per block per step, AFTER the flag is seen
        (void)__hip_atomic_load(cp, __ATOMIC_ACQUIRE, __HIP_MEMORY_SCOPE_AGENT);
      }
      __syncthreads();   // all waves' h-loads ordered after the invalidate
    }

    // ---- stage h_t (bf16 copy): 16 rows x 256 m ----
    {
      const unsigned short* src = HS + ((size_t)t*Bsz + b0 + srow)*512 + sh_m;
      const uint4 va = *(const uint4*)(src);
      const uint4 vb = *(const uint4*)(src + 8);
      const int base = (sh_m>>5)*512 + srow*32 + (sh_m & 31);
      *(uint4*)&Ha[base]     = va;
      *(uint4*)&Ha[base + 8] = vb;
    }
    __syncthreads();   // Ha ready

    // ---- h_t @ Wr : chunks 4..11 ----
    #pragma unroll
    for (int c = 0; c < 8; ++c){
      const short8 af = *(const short8*)&Ha[c*512 + arow];
      acc0 = __builtin_amdgcn_mfma_f32_16x16x32_bf16(af, wf[c+4][0], acc0, 0, 0, 0);
      acc1 = __builtin_amdgcn_mfma_f32_16x16x32_bf16(af, wf[c+4][1], acc1, 0, 0, 0);
      acc2 = __builtin_amdgcn_mfma_f32_16x16x32_bf16(af, wf[c+4][2], acc2, 0, 0, 0);
      acc3 = __builtin_amdgcn_mfma_f32_16x16x32_bf16(af, wf[c+4][3], acc3, 0, 0, 0);
    }

    // ---- gate update (in-register; C layout: col=nl, row=kq*4+r) ----
    #pragma unroll
    for (int r = 0; r < 4; ++r){
      const float ig = sigmoid_fast(acc0[r] + bi[0]);
      const float fg = sigmoid_fast(acc1[r] + bi[1]);
      const float gg = tanh_fast  (acc2[r] + bi[2]);
      const float og = sigmoid_fast(acc3[r] + bi[3]);
      const float s1 = fmaf(fg, s_reg[r], ig * gg);
      s_reg[r] = s1;
      const float hn = og * tanh_fast(s1);
      unsigned short* rp = HS + ((size_t)(t+1)*Bsz + b0 + r0 + r)*512;
      rp[ucol]       = bf16r(hn);
      rp[256 + ucol] = bf16r(s1);
    }

    // ---- publish h_{t+1}: drain writes, then one release-add per block ----
    __syncthreads();
    if (tid == 0)
      __hip_atomic_fetch_add(&ctr[t*32 + bgq], 1, __ATOMIC_RELEASE,
                             __HIP_MEMORY_SCOPE_AGENT);
  }
}

// ---------------------------------------------------------------------------
// K3: attention v2 — register-tiled e-loop.
// Block = (b, 16 t's). XCD-swizzled block->(b,t0) map (same-b blocks co-located
// + co-temporal on one XCD -> Q[b] L2-resident).
// Phase 1: HS bf16 -> fp32 HSl (conflict-free map); r1 GEMM -> Pl = exp(2*r1).
// Phase 2: u-chunked (64): stage Qu[128][68]; each thread owns a 2t x 4n tile,
//   acc[2][4] += ve_u * rcp(1 + P*Q) over u. 7 b128 per 32 rcp (was 3 per 4).
// Softmax fully in registers via __shfl_xor within 32-lane groups.
// LDS: Pl 16.6K | union{HSl 32K, Qu 34.8K} | vel 1K = 51.25 KB -> 3 blocks/CU.
// ---------------------------------------------------------------------------
__global__ __launch_bounds__(256) void k_attn(const unsigned short* __restrict__ HS,
                                              const float* __restrict__ Q,
                                              const float* __restrict__ We,
                                              const float* __restrict__ ve,
                                              const float* __restrict__ x,
                                              float* __restrict__ out){
  // XCD-aware swizzle: wgid -> l = xcd*1024 + idx; b = l>>4 (64 b's per XCD),
  // t0g = l&15 (same-b blocks consecutive in dispatch order).
  const unsigned wgid = blockIdx.x + (blockIdx.y << 9);
  const unsigned l    = ((wgid & 7u) << 10) + (wgid >> 3);
  const int b  = (int)(l >> 4);
  const int t0 = (int)(l & 15u) << 4;

  __shared__ __align__(16) char smem[52480];
  float* Pl  = (float*)smem;               // [16][260] fp32
  float* HSl = (float*)(smem + 16640);     // [16][512] fp32 (phase 1)
  float* Qu  = (float*)(smem + 16640);     // [128][68] fp32 (phase 2, aliases HSl)
  float* vel = (float*)(smem + 51456);     // [256]

  const int tid = threadIdx.x;
  vel[tid] = ve[tid];

  // ---- stage HS -> HSl fp32 (lane-linear writes: conflict-free) ----
  #pragma unroll
  for (int i2 = 0; i2 < 8; ++i2){
    const int seg = i2*256 + tid;          // 0..2047
    const int row = seg >> 7;              // 0..15
    const int q   = seg & 127;             // 0..127 float4-quads
    const ushort4 v = *(const ushort4*)(HS + ((size_t)(t0 + row)*Bsz + b)*512 + q*4);
    float4 f;
    f.x = __uint_as_float((unsigned)v.x << 16);
    f.y = __uint_as_float((unsigned)v.y << 16);
    f.z = __uint_as_float((unsigned)v.z << 16);
    f.w = __uint_as_float((unsigned)v.w << 16);
    *(float4*)&HSl[row*512 + q*4] = f;
  }
  __syncthreads();

  // ---- r1 GEMM: P[t][u] = exp(2 * [h|s] @ We) ----
  {
    const int lane = tid & 63;
    const int w    = tid >> 6;
    float acc[4][4] = {};
    for (int k = 0; k < 2*Msz; k += 4){
      float a[4][4];
      #pragma unroll
      for (int ri = 0; ri < 4; ++ri){
        const float4 t4 = *(const float4*)&HSl[(w + 4*ri)*512 + k];
        a[ri][0]=t4.x; a[ri][1]=t4.y; a[ri][2]=t4.z; a[ri][3]=t4.w;
      }
      #pragma unroll
      for (int kk = 0; kk < 4; ++kk){
        const float4 wv = *(const float4*)(We + (size_t)(k+kk) * Tsz + lane*4);
        const float wa[4] = {wv.x, wv.y, wv.z, wv.w};
        #pragma unroll
        for (int ri=0; ri<4; ++ri)
          #pragma unroll
          for (int j=0;j<4;++j)
            acc[ri][j] = fmaf(a[ri][kk], wa[j], acc[ri][j]);
      }
    }
    #pragma unroll
    for (int ri = 0; ri < 4; ++ri){
      float4 v;
      v.x = __expf(2.0f*acc[ri][0]);
      v.y = __expf(2.0f*acc[ri][1]);
      v.z = __expf(2.0f*acc[ri][2]);
      v.w = __expf(2.0f*acc[ri][3]);
      *(float4*)&Pl[(w + 4*ri)*260 + lane*4] = v;   // uniform row: linear b128
    }
  }

  // ---- e-loop: thread tile = t rows {2tt, 2tt+1} x n cols {tn + 32r} ----
  const int tt = tid >> 5;                 // 0..7
  const int tn = tid & 31;                 // 0..31
  float acc[2][4] = {};
  const float* Qb = Q + (size_t)b * Nsz * Tsz;

  for (int u0 = 0; u0 < Tsz; u0 += 64){
    __syncthreads();                       // prior readers of region done
    #pragma unroll
    for (int i2 = 0; i2 < 8; ++i2){
      const int seg = i2*256 + tid;        // 0..2047
      const int row = seg >> 4;            // 0..127
      const int q   = seg & 15;            // 0..15
      *(float4*)&Qu[row*68 + q*4] = *(const float4*)&Qb[row*256 + u0 + q*4];
    }
    __syncthreads();
    #pragma unroll 4
    for (int us = 0; us < 16; ++us){
      const int uu = u0 + us*4;
      const float4 ve4 = *(const float4*)&vel[uu];
      const float4 p0  = *(const float4*)&Pl[(2*tt+0)*260 + uu];
      const float4 p1  = *(const float4*)&Pl[(2*tt+1)*260 + uu];
      #pragma unroll
      for (int r = 0; r < 4; ++r){
        const float4 qv = *(const float4*)&Qu[(tn + 32*r)*68 + us*4];
        acc[0][r] = fmaf(ve4.x, rcp_fast(fmaf(p0.x, qv.x, 1.0f)), acc[0][r]);
        acc[0][r] = fmaf(ve4.y, rcp_fast(fmaf(p0.y, qv.y, 1.0f)), acc[0][r]);
        acc[0][r] = fmaf(ve4.z, rcp_fast(fmaf(p0.z, qv.z, 1.0f)), acc[0][r]);
        acc[0][r] = fmaf(ve4.w, rcp_fast(fmaf(p0.w, qv.w, 1.0f)), acc[0][r]);
        acc[1][r] = fmaf(ve4.x, rcp_fast(fmaf(p1.x, qv.x, 1.0f)), acc[1][r]);
        acc[1][r] = fmaf(ve4.y, rcp_fast(fmaf(p1.y, qv.y, 1.0f)), acc[1][r]);
        acc[1][r] = fmaf(ve4.z, rcp_fast(fmaf(p1.z, qv.z, 1.0f)), acc[1][r]);
        acc[1][r] = fmaf(ve4.w, rcp_fast(fmaf(p1.w, qv.w, 1.0f)), acc[1][r]);
      }
    }
  }

  // ---- softmax in registers: row t = 2tt+i lives in one 32-lane group ----
  float ex[2][4];
  float m0 = -3.0e38f, m1 = -3.0e38f;
  #pragma unroll
  for (int r = 0; r < 4; ++r){
    ex[0][r] = -2.0f * acc[0][r];
    ex[1][r] = -2.0f * acc[1][r];
    m0 = fmaxf(m0, ex[0][r]);
    m1 = fmaxf(m1, ex[1][r]);
  }
  #pragma unroll
  for (int mk = 16; mk >= 1; mk >>= 1){
    m0 = fmaxf(m0, __shfl_xor(m0, mk, 64));
    m1 = fmaxf(m1, __shfl_xor(m1, mk, 64));
  }
  float s0 = 0.0f, s1 = 0.0f;
  #pragma unroll
  for (int r = 0; r < 4; ++r){
    const float p0 = __expf(ex[0][r] - m0);
    const float p1 = __expf(ex[1][r] - m1);
    ex[0][r] = p0; ex[1][r] = p1;
    s0 += p0; s1 += p1;
  }
  #pragma unroll
  for (int mk = 16; mk >= 1; mk >>= 1){
    s0 += __shfl_xor(s0, mk, 64);
    s1 += __shfl_xor(s1, mk, 64);
  }
  const float inv0 = rcp_fast(s0);
  const float inv1 = rcp_fast(s1);

  #pragma unroll
  for (int r = 0; r < 4; ++r){
    const size_t i0 = ((size_t)b*Tsz + t0 + 2*tt + 0)*Nsz + tn + 32*r;
    const size_t i1 = ((size_t)b*Tsz + t0 + 2*tt + 1)*Nsz + tn + 32*r;
    out[i0] = ex[0][r] * inv0 * x[i0];
    out[i1] = ex[1][r] * inv1 * x[i1];
  }
}

// ---------------------------------------------------------------------------
extern "C" void kernel_launch(void* const* d_in, const int* in_sizes, int n_in,
                              void* d_out, int out_size, void* d_ws, size_t ws_size,
                              hipStream_t stream){
  const float* x    = (const float*)d_in[0];
  const float* s_in = (const float*)d_in[1];
  const float* h_in = (const float*)d_in[2];
  const float* We   = (const float*)d_in[3];
  const float* Ue   = (const float*)d_in[4];
  const float* ve   = (const float*)d_in[5];
  const float* Wk   = (const float*)d_in[6];
  const float* Wr   = (const float*)d_in[7];
  const float* bias = (const float*)d_in[8];
  float* out = (float*)d_out;

  // ws layout (~201.4 MB): Q fp32 67MB | HS bf16 134MB | ctr 32KB
  float* Q = (float*)d_ws;
  unsigned short* HS = (unsigned short*)(Q + (size_t)Bsz*Nsz*Tsz);
  int* ctr = (int*)(HS + (size_t)Tsz*Bsz*512);

  k_init<<<(Bsz*Msz)/256, 256, 0, stream>>>(h_in, s_in, HS, ctr);
  k_r2exp<<<dim3(Bsz, 8), 256, 0, stream>>>(x, Ue, Q);
  k_scan<<<128, 256, 0, stream>>>(x, Wk, Wr, bias, s_in, HS, ctr);
  k_attn<<<dim3(Bsz, Tsz/16), 256, 0, stream>>>(HS, Q, We, ve, x, out);
}

// Round 4
// 1874.798 us; speedup vs baseline: 1.9447x; 1.2786x over previous
//
#include <hip/hip_runtime.h>

static constexpr int Bsz = 512;
static constexpr int Tsz = 256;
static constexpr int Nsz = 128;
static constexpr int Msz = 256;

using short8 = __attribute__((ext_vector_type(8))) short;
using f32x4  = __attribute__((ext_vector_type(4))) float;

__device__ __forceinline__ float rcp_fast(float v){ return __builtin_amdgcn_rcpf(v); }
__device__ __forceinline__ float sigmoid_fast(float v){ return rcp_fast(1.0f + __expf(-v)); }
__device__ __forceinline__ float tanh_fast(float v){ return 1.0f - 2.0f * rcp_fast(1.0f + __expf(2.0f * v)); }
__device__ __forceinline__ unsigned short bf16r(float f){
  unsigned u = __float_as_uint(f);
  u += 0x7FFFu + ((u >> 16) & 1u);
  return (unsigned short)(u >> 16);
}

// ---------------------------------------------------------------------------
// HS layout (NEW, unit-interleaved): HS[t][b] = 256 uints; uint[u] = h|s<<16.
// h/s written with sc0 sc1 (write-through to MALL) by k_scan; read with
// sc0 sc1 by the consumer -> NO buffer_wbl2 / buffer_inv in the scan loop.
// ---------------------------------------------------------------------------

// K0: HS slab t=0 + zero the scan barrier counters.
__global__ __launch_bounds__(256) void k_init(const float* __restrict__ h_in,
                                              const float* __restrict__ s_in,
                                              unsigned short* __restrict__ HS,
                                              int* __restrict__ ctr){
  const int i = blockIdx.x * 256 + threadIdx.x;   // 0 .. B*M-1 (131072)
  if (i < 8192) ctr[i] = 0;
  const float h = h_in[i];
  const float s = s_in[i];
  const int b = i >> 8;
  const int m = i & 255;
  unsigned* row = (unsigned*)(HS + (size_t)b * 512);
  row[m] = (unsigned)bf16r(h) | ((unsigned)bf16r(s) << 16);
}

// ---------------------------------------------------------------------------
// K1: Q[b][n][u] = exp( 2 * sum_t x[b][t][n] * Ue[t][u] )   (r2, pre-exp'd)
// ---------------------------------------------------------------------------
__global__ __launch_bounds__(256) void k_r2exp(const float* __restrict__ x,
                                               const float* __restrict__ Ue,
                                               float* __restrict__ Q){
  const int b  = blockIdx.x;
  const int n0 = (blockIdx.y >> 2) * 64;
  const int u0 = (blockIdx.y & 3) * 64;
  __shared__ float Al[16][68];
  __shared__ float Bl[16][68];
  const int tid  = threadIdx.x;
  const int lane = tid & 63;
  const int kq   = tid >> 6;
  const int ty   = tid >> 4;
  const int tx   = tid & 15;
  float acc[4][4] = {};
  const float* xb = x + (size_t)b * Tsz * Nsz;
  for (int k0 = 0; k0 < Tsz; k0 += 16){
    #pragma unroll
    for (int i = 0; i < 4; ++i){
      const int k = kq*4 + i;
      Al[k][lane] = xb[(size_t)(k0+k)*Nsz + n0 + lane];
      Bl[k][lane] = Ue[(size_t)(k0+k)*Tsz + u0 + lane];
    }
    __syncthreads();
    #pragma unroll
    for (int kk = 0; kk < 16; ++kk){
      const float4 a = *(const float4*)&Al[kk][ty*4];
      const float4 w = *(const float4*)&Bl[kk][tx*4];
      const float av[4] = {a.x,a.y,a.z,a.w};
      const float wv[4] = {w.x,w.y,w.z,w.w};
      #pragma unroll
      for (int i=0;i<4;++i)
        #pragma unroll
        for (int j=0;j<4;++j)
          acc[i][j] = fmaf(av[i], wv[j], acc[i][j]);
    }
    __syncthreads();
  }
  float* Qb = Q + (size_t)b * Nsz * Tsz;
  #pragma unroll
  for (int i=0;i<4;++i){
    float4 v;
    v.x = __expf(2.0f*acc[i][0]);
    v.y = __expf(2.0f*acc[i][1]);
    v.z = __expf(2.0f*acc[i][2]);
    v.w = __expf(2.0f*acc[i][3]);
    *(float4*)&Qb[(size_t)(n0 + ty*4 + i)*Tsz + u0 + tx*4] = v;
  }
}

// ---------------------------------------------------------------------------
// K2: persistent LSTM scan, v4 (zero cache-maintenance sync).
// Grid 128 = 32 batch-groups (16 b) x 4 unit-groups (64 units).
// Per step: stage x_t + x@Wk MFMAs (h-independent); tid0 relaxed spin on flag;
// h_t loaded with sc0 sc1 (MALL-coherent, no L2 inv); h@Wr; gates; h/s stored
// with sc0 sc1 (write-through, no L2 flush); vmcnt(0); barrier; relaxed
// fetch_add. No buffer_wbl2 / buffer_inv anywhere in the loop.
// ---------------------------------------------------------------------------
__global__ __launch_bounds__(256, 1) void k_scan(const float* __restrict__ x,
                                                 const float* __restrict__ Wk,
                                                 const float* __restrict__ Wr,
                                                 const float* __restrict__ bias,
                                                 const float* __restrict__ s_in,
                                                 unsigned short* __restrict__ HS,
                                                 int* __restrict__ ctr){
  const int bgq = blockIdx.x & 31;    // batch group 0..31 (16 batches)
  const int ug  = blockIdx.x >> 5;    // unit group 0..3 (64 units)
  const int b0  = bgq * 16;
  const int u0  = ug * 64;
  const int tid  = threadIdx.x;
  const int w    = tid >> 6;          // wave 0..3 -> units u0+16w..
  const int lane = tid & 63;
  const int nl   = lane & 15;
  const int kq   = lane >> 4;

  __shared__ unsigned short Xa[4*16*32];   // x_t chunks (k=0..127),   4 KB
  __shared__ unsigned short Ha[8*16*32];   // h_t chunks (k=128..383), 8 KB

  const int ucol = u0 + (w<<4) + nl;       // this lane's unit column

  // ---- preload W fragments (bf16) into registers: 12 chunks x 4 gates ----
  short8 wf[12][4];
  #pragma unroll
  for (int c = 0; c < 12; ++c){
    #pragma unroll
    for (int g = 0; g < 4; ++g){
      const int jcol = g*Msz + ucol;
      short8 f;
      #pragma unroll
      for (int j = 0; j < 8; ++j){
        const int k = c*32 + kq*8 + j;
        const float wv = (k < Nsz) ? Wk[(size_t)k*(4*Msz) + jcol]
                                   : Wr[(size_t)(k - Nsz)*(4*Msz) + jcol];
        f[j] = (short)bf16r(wv);
      }
      wf[c][g] = f;
    }
  }

  // ---- per-lane state: 4 batch rows x 1 unit ----
  const int r0 = kq*4;                     // first of 4 batch rows (C layout)
  float bi[4];
  #pragma unroll
  for (int g = 0; g < 4; ++g) bi[g] = bias[g*Msz + ucol];
  float s_reg[4];
  #pragma unroll
  for (int r = 0; r < 4; ++r)
    s_reg[r] = s_in[(size_t)(b0 + r0 + r)*Msz + ucol];

  // staging indices (256 threads cover 16 rows x full width)
  const int srow = tid >> 4;               // 0..15
  const int sx_n = (tid & 15) * 8;         // x col base (8 fp32)
  const int sh_m = (tid & 15) * 16;        // h col base (16 units)
  const int arow = nl*32 + kq*8;           // A-fragment LDS offset (shorts)

  #pragma unroll 1
  for (int t = 0; t < Tsz - 1; ++t){
    // ---- stage x_t (no dependence on the group barrier) ----
    {
      const float* xp = x + ((size_t)(b0+srow)*Tsz + t)*Nsz + sx_n;
      const float4 v0 = *(const float4*)(xp);
      const float4 v1 = *(const float4*)(xp + 4);
      ushort4 o0, o1;
      o0.x = bf16r(v0.x); o0.y = bf16r(v0.y); o0.z = bf16r(v0.z); o0.w = bf16r(v0.w);
      o1.x = bf16r(v1.x); o1.y = bf16r(v1.y); o1.z = bf16r(v1.z); o1.w = bf16r(v1.w);
      const int base = (sx_n>>5)*512 + srow*32 + (sx_n & 31);
      *(ushort4*)&Xa[base]     = o0;
      *(ushort4*)&Xa[base + 4] = o1;
    }
    __syncthreads();   // Xa ready

    // ---- x_t @ Wk : chunks 0..3 (overlaps producers still finishing h_t) ----
    f32x4 acc0 = {0.f,0.f,0.f,0.f}, acc1 = {0.f,0.f,0.f,0.f};
    f32x4 acc2 = {0.f,0.f,0.f,0.f}, acc3 = {0.f,0.f,0.f,0.f};
    #pragma unroll
    for (int c = 0; c < 4; ++c){
      const short8 af = *(const short8*)&Xa[c*512 + arow];
      acc0 = __builtin_amdgcn_mfma_f32_16x16x32_bf16(af, wf[c][0], acc0, 0, 0, 0);
      acc1 = __builtin_amdgcn_mfma_f32_16x16x32_bf16(af, wf[c][1], acc1, 0, 0, 0);
      acc2 = __builtin_amdgcn_mfma_f32_16x16x32_bf16(af, wf[c][2], acc2, 0, 0, 0);
      acc3 = __builtin_amdgcn_mfma_f32_16x16x32_bf16(af, wf[c][3], acc3, 0, 0, 0);
    }

    // ---- wait for h_t: tid0 relaxed spin (no cache ops), then barrier ----
    if (t > 0){
      if (tid == 0){
        int* cp = &ctr[(t-1)*32 + bgq];
        while (__hip_atomic_load(cp, __ATOMIC_RELAXED, __HIP_MEMORY_SCOPE_AGENT) < 4)
          __builtin_amdgcn_s_sleep(1);
      }
      __syncthreads();
    }

    // ---- stage h_t: sc0 sc1 loads (MALL-coherent), extract h (low16) ----
    {
      const unsigned* hp = (const unsigned*)(HS + ((size_t)t*Bsz + b0 + srow)*512) + sh_m;
      uint4 a0, a1, a2, a3;
      asm volatile(
        "global_load_dwordx4 %0, %4, off sc0 sc1\n\t"
        "global_load_dwordx4 %1, %4, off offset:16 sc0 sc1\n\t"
        "global_load_dwordx4 %2, %4, off offset:32 sc0 sc1\n\t"
        "global_load_dwordx4 %3, %4, off offset:48 sc0 sc1\n\t"
        "s_waitcnt vmcnt(0)"
        : "=&v"(a0), "=&v"(a1), "=&v"(a2), "=&v"(a3)
        : "v"(hp)
        : "memory");
      ushort4 h0, h1, h2, h3;
      h0.x=(unsigned short)a0.x; h0.y=(unsigned short)a0.y; h0.z=(unsigned short)a0.z; h0.w=(unsigned short)a0.w;
      h1.x=(unsigned short)a1.x; h1.y=(unsigned short)a1.y; h1.z=(unsigned short)a1.z; h1.w=(unsigned short)a1.w;
      h2.x=(unsigned short)a2.x; h2.y=(unsigned short)a2.y; h2.z=(unsigned short)a2.z; h2.w=(unsigned short)a2.w;
      h3.x=(unsigned short)a3.x; h3.y=(unsigned short)a3.y; h3.z=(unsigned short)a3.z; h3.w=(unsigned short)a3.w;
      const int base = (sh_m>>5)*512 + srow*32 + (sh_m & 31);
      *(ushort4*)&Ha[base +  0] = h0;
      *(ushort4*)&Ha[base +  4] = h1;
      *(ushort4*)&Ha[base +  8] = h2;
      *(ushort4*)&Ha[base + 12] = h3;
    }
    __syncthreads();   // Ha ready

    // ---- h_t @ Wr : chunks 4..11 ----
    #pragma unroll
    for (int c = 0; c < 8; ++c){
      const short8 af = *(const short8*)&Ha[c*512 + arow];
      acc0 = __builtin_amdgcn_mfma_f32_16x16x32_bf16(af, wf[c+4][0], acc0, 0, 0, 0);
      acc1 = __builtin_amdgcn_mfma_f32_16x16x32_bf16(af, wf[c+4][1], acc1, 0, 0, 0);
      acc2 = __builtin_amdgcn_mfma_f32_16x16x32_bf16(af, wf[c+4][2], acc2, 0, 0, 0);
      acc3 = __builtin_amdgcn_mfma_f32_16x16x32_bf16(af, wf[c+4][3], acc3, 0, 0, 0);
    }

    // ---- gate update; pack (h,s) per unit; sc0 sc1 write-through stores ----
    {
      unsigned hv[4];
      #pragma unroll
      for (int r = 0; r < 4; ++r){
        const float ig = sigmoid_fast(acc0[r] + bi[0]);
        const float fg = sigmoid_fast(acc1[r] + bi[1]);
        const float gg = tanh_fast  (acc2[r] + bi[2]);
        const float og = sigmoid_fast(acc3[r] + bi[3]);
        const float s1 = fmaf(fg, s_reg[r], ig * gg);
        s_reg[r] = s1;
        const float hn = og * tanh_fast(s1);
        hv[r] = (unsigned)bf16r(hn) | ((unsigned)bf16r(s1) << 16);
      }
      unsigned* gp = (unsigned*)(HS + ((size_t)(t+1)*Bsz + b0 + r0)*512) + ucol;
      asm volatile(
        "global_store_dword %0, %1, off sc0 sc1\n\t"
        "global_store_dword %0, %2, off offset:1024 sc0 sc1\n\t"
        "global_store_dword %0, %3, off offset:2048 sc0 sc1\n\t"
        "global_store_dword %0, %4, off offset:3072 sc0 sc1\n\t"
        "s_waitcnt vmcnt(0)"
        :: "v"(gp), "v"(hv[0]), "v"(hv[1]), "v"(hv[2]), "v"(hv[3])
        : "memory");
    }

    // ---- publish: stores already at MALL -> relaxed flag add ----
    __syncthreads();
    if (tid == 0)
      __hip_atomic_fetch_add(&ctr[t*32 + bgq], 1, __ATOMIC_RELAXED,
                             __HIP_MEMORY_SCOPE_AGENT);
  }
}

// ---------------------------------------------------------------------------
// K3: attention v2 — register-tiled e-loop (unchanged except HS unpack for
// the new unit-interleaved layout).
// ---------------------------------------------------------------------------
__global__ __launch_bounds__(256) void k_attn(const unsigned short* __restrict__ HS,
                                              const float* __restrict__ Q,
                                              const float* __restrict__ We,
                                              const float* __restrict__ ve,
                                              const float* __restrict__ x,
                                              float* __restrict__ out){
  const unsigned wgid = blockIdx.x + (blockIdx.y << 9);
  const unsigned l    = ((wgid & 7u) << 10) + (wgid >> 3);
  const int b  = (int)(l >> 4);
  const int t0 = (int)(l & 15u) << 4;

  __shared__ __align__(16) char smem[52480];
  float* Pl  = (float*)smem;               // [16][260] fp32
  float* HSl = (float*)(smem + 16640);     // [16][512] fp32 (phase 1)
  float* Qu  = (float*)(smem + 16640);     // [128][68] fp32 (phase 2, aliases)
  float* vel = (float*)(smem + 51456);     // [256]

  const int tid = threadIdx.x;
  vel[tid] = ve[tid];

  // ---- stage HS -> HSl fp32 (interleaved unpack: low16=h, high16=s) ----
  #pragma unroll
  for (int i2 = 0; i2 < 4; ++i2){
    const int seg = i2*256 + tid;          // 0..1023
    const int row = seg >> 6;              // 0..15
    const int q   = seg & 63;              // uint4 group (4 units)
    const unsigned* src = (const unsigned*)(HS + ((size_t)(t0 + row)*Bsz + b)*512) + q*4;
    const uint4 v = *(const uint4*)src;
    const unsigned wv[4] = {v.x, v.y, v.z, v.w};
    float4 hf, sf;
    hf.x = __uint_as_float(wv[0] << 16);  sf.x = __uint_as_float(wv[0] & 0xFFFF0000u);
    hf.y = __uint_as_float(wv[1] << 16);  sf.y = __uint_as_float(wv[1] & 0xFFFF0000u);
    hf.z = __uint_as_float(wv[2] << 16);  sf.z = __uint_as_float(wv[2] & 0xFFFF0000u);
    hf.w = __uint_as_float(wv[3] << 16);  sf.w = __uint_as_float(wv[3] & 0xFFFF0000u);
    *(float4*)&HSl[row*512 + q*4]       = hf;
    *(float4*)&HSl[row*512 + 256 + q*4] = sf;
  }
  __syncthreads();

  // ---- r1 GEMM: P[t][u] = exp(2 * [h|s] @ We) ----
  {
    const int lane = tid & 63;
    const int w    = tid >> 6;
    float acc[4][4] = {};
    for (int k = 0; k < 2*Msz; k += 4){
      float a[4][4];
      #pragma unroll
      for (int ri = 0; ri < 4; ++ri){
        const float4 t4 = *(const float4*)&HSl[(w + 4*ri)*512 + k];
        a[ri][0]=t4.x; a[ri][1]=t4.y; a[ri][2]=t4.z; a[ri][3]=t4.w;
      }
      #pragma unroll
      for (int kk = 0; kk < 4; ++kk){
        const float4 wv = *(const float4*)(We + (size_t)(k+kk) * Tsz + lane*4);
        const float wa[4] = {wv.x, wv.y, wv.z, wv.w};
        #pragma unroll
        for (int ri=0; ri<4; ++ri)
          #pragma unroll
          for (int j=0;j<4;++j)
            acc[ri][j] = fmaf(a[ri][kk], wa[j], acc[ri][j]);
      }
    }
    #pragma unroll
    for (int ri = 0; ri < 4; ++ri){
      float4 v;
      v.x = __expf(2.0f*acc[ri][0]);
      v.y = __expf(2.0f*acc[ri][1]);
      v.z = __expf(2.0f*acc[ri][2]);
      v.w = __expf(2.0f*acc[ri][3]);
      *(float4*)&Pl[(w + 4*ri)*260 + lane*4] = v;
    }
  }

  // ---- e-loop: thread tile = t rows {2tt, 2tt+1} x n cols {tn + 32r} ----
  const int tt = tid >> 5;                 // 0..7
  const int tn = tid & 31;                 // 0..31
  float acc[2][4] = {};
  const float* Qb = Q + (size_t)b * Nsz * Tsz;

  for (int u0 = 0; u0 < Tsz; u0 += 64){
    __syncthreads();
    #pragma unroll
    for (int i2 = 0; i2 < 8; ++i2){
      const int seg = i2*256 + tid;        // 0..2047
      const int row = seg >> 4;            // 0..127
      const int q   = seg & 15;            // 0..15
      *(float4*)&Qu[row*68 + q*4] = *(const float4*)&Qb[row*256 + u0 + q*4];
    }
    __syncthreads();
    #pragma unroll 4
    for (int us = 0; us < 16; ++us){
      const int uu = u0 + us*4;
      const float4 ve4 = *(const float4*)&vel[uu];
      const float4 p0  = *(const float4*)&Pl[(2*tt+0)*260 + uu];
      const float4 p1  = *(const float4*)&Pl[(2*tt+1)*260 + uu];
      #pragma unroll
      for (int r = 0; r < 4; ++r){
        const float4 qv = *(const float4*)&Qu[(tn + 32*r)*68 + us*4];
        acc[0][r] = fmaf(ve4.x, rcp_fast(fmaf(p0.x, qv.x, 1.0f)), acc[0][r]);
        acc[0][r] = fmaf(ve4.y, rcp_fast(fmaf(p0.y, qv.y, 1.0f)), acc[0][r]);
        acc[0][r] = fmaf(ve4.z, rcp_fast(fmaf(p0.z, qv.z, 1.0f)), acc[0][r]);
        acc[0][r] = fmaf(ve4.w, rcp_fast(fmaf(p0.w, qv.w, 1.0f)), acc[0][r]);
        acc[1][r] = fmaf(ve4.x, rcp_fast(fmaf(p1.x, qv.x, 1.0f)), acc[1][r]);
        acc[1][r] = fmaf(ve4.y, rcp_fast(fmaf(p1.y, qv.y, 1.0f)), acc[1][r]);
        acc[1][r] = fmaf(ve4.z, rcp_fast(fmaf(p1.z, qv.z, 1.0f)), acc[1][r]);
        acc[1][r] = fmaf(ve4.w, rcp_fast(fmaf(p1.w, qv.w, 1.0f)), acc[1][r]);
      }
    }
  }

  // ---- softmax in registers (row t in one 32-lane group) ----
  float ex[2][4];
  float m0 = -3.0e38f, m1 = -3.0e38f;
  #pragma unroll
  for (int r = 0; r < 4; ++r){
    ex[0][r] = -2.0f * acc[0][r];
    ex[1][r] = -2.0f * acc[1][r];
    m0 = fmaxf(m0, ex[0][r]);
    m1 = fmaxf(m1, ex[1][r]);
  }
  #pragma unroll
  for (int mk = 16; mk >= 1; mk >>= 1){
    m0 = fmaxf(m0, __shfl_xor(m0, mk, 64));
    m1 = fmaxf(m1, __shfl_xor(m1, mk, 64));
  }
  float s0 = 0.0f, s1 = 0.0f;
  #pragma unroll
  for (int r = 0; r < 4; ++r){
    const float p0 = __expf(ex[0][r] - m0);
    const float p1 = __expf(ex[1][r] - m1);
    ex[0][r] = p0; ex[1][r] = p1;
    s0 += p0; s1 += p1;
  }
  #pragma unroll
  for (int mk = 16; mk >= 1; mk >>= 1){
    s0 += __shfl_xor(s0, mk, 64);
    s1 += __shfl_xor(s1, mk, 64);
  }
  const float inv0 = rcp_fast(s0);
  const float inv1 = rcp_fast(s1);

  #pragma unroll
  for (int r = 0; r < 4; ++r){
    const size_t i0 = ((size_t)b*Tsz + t0 + 2*tt + 0)*Nsz + tn + 32*r;
    const size_t i1 = ((size_t)b*Tsz + t0 + 2*tt + 1)*Nsz + tn + 32*r;
    out[i0] = ex[0][r] * inv0 * x[i0];
    out[i1] = ex[1][r] * inv1 * x[i1];
  }
}

// ---------------------------------------------------------------------------
extern "C" void kernel_launch(void* const* d_in, const int* in_sizes, int n_in,
                              void* d_out, int out_size, void* d_ws, size_t ws_size,
                              hipStream_t stream){
  const float* x    = (const float*)d_in[0];
  const float* s_in = (const float*)d_in[1];
  const float* h_in = (const float*)d_in[2];
  const float* We   = (const float*)d_in[3];
  const float* Ue   = (const float*)d_in[4];
  const float* ve   = (const float*)d_in[5];
  const float* Wk   = (const float*)d_in[6];
  const float* Wr   = (const float*)d_in[7];
  const float* bias = (const float*)d_in[8];
  float* out = (float*)d_out;

  // ws layout (~201.4 MB): Q fp32 67MB | HS 134MB | ctr 32KB
  float* Q = (float*)d_ws;
  unsigned short* HS = (unsigned short*)(Q + (size_t)Bsz*Nsz*Tsz);
  int* ctr = (int*)(HS + (size_t)Tsz*Bsz*512);

  k_init<<<(Bsz*Msz)/256, 256, 0, stream>>>(h_in, s_in, HS, ctr);
  k_r2exp<<<dim3(Bsz, 8), 256, 0, stream>>>(x, Ue, Q);
  k_scan<<<128, 256, 0, stream>>>(x, Wk, Wr, bias, s_in, HS, ctr);
  k_attn<<<dim3(Bsz, Tsz/16), 256, 0, stream>>>(HS, Q, We, ve, x, out);
}

// Round 5
// 1641.522 us; speedup vs baseline: 2.2211x; 1.1421x over previous
//
#include <hip/hip_runtime.h>

static constexpr int Bsz = 512;
static constexpr int Tsz = 256;
static constexpr int Nsz = 128;
static constexpr int Msz = 256;

using short8  = __attribute__((ext_vector_type(8))) short;
using ushort8v= __attribute__((ext_vector_type(8))) unsigned short;
using f32x4   = __attribute__((ext_vector_type(4))) float;

__device__ __forceinline__ float rcp_fast(float v){ return __builtin_amdgcn_rcpf(v); }
__device__ __forceinline__ float sigmoid_fast(float v){ return rcp_fast(1.0f + __expf(-v)); }
__device__ __forceinline__ float tanh_fast(float v){ return 1.0f - 2.0f * rcp_fast(1.0f + __expf(2.0f * v)); }
__device__ __forceinline__ unsigned short bf16r(float f){
  unsigned u = __float_as_uint(f);
  u += 0x7FFFu + ((u >> 16) & 1u);
  return (unsigned short)(u >> 16);
}

// ---------------------------------------------------------------------------
// HS layout (unit-interleaved): HS[t][b] = 256 uints; uint[u] = h|s<<16.
// Written sc0 sc1 (write-through to MALL) by k_scan; read sc0 sc1 in-loop.
// ---------------------------------------------------------------------------

// K0: HS slab t=0 + zero the scan barrier counters.
__global__ __launch_bounds__(256) void k_init(const float* __restrict__ h_in,
                                              const float* __restrict__ s_in,
                                              unsigned short* __restrict__ HS,
                                              int* __restrict__ ctr){
  const int i = blockIdx.x * 256 + threadIdx.x;   // 0 .. B*M-1 (131072)
  if (i < 8192) ctr[i] = 0;
  const float h = h_in[i];
  const float s = s_in[i];
  const int b = i >> 8;
  const int m = i & 255;
  unsigned* row = (unsigned*)(HS + (size_t)b * 512);
  row[m] = (unsigned)bf16r(h) | ((unsigned)bf16r(s) << 16);
}

// ---------------------------------------------------------------------------
// K1: Q[b][n][u] = exp( 2 * sum_t x[b][t][n] * Ue[t][u] )   (r2, pre-exp'd)
// ---------------------------------------------------------------------------
__global__ __launch_bounds__(256) void k_r2exp(const float* __restrict__ x,
                                               const float* __restrict__ Ue,
                                               float* __restrict__ Q){
  const int b  = blockIdx.x;
  const int n0 = (blockIdx.y >> 2) * 64;
  const int u0 = (blockIdx.y & 3) * 64;
  __shared__ float Al[16][68];
  __shared__ float Bl[16][68];
  const int tid  = threadIdx.x;
  const int lane = tid & 63;
  const int kq   = tid >> 6;
  const int ty   = tid >> 4;
  const int tx   = tid & 15;
  float acc[4][4] = {};
  const float* xb = x + (size_t)b * Tsz * Nsz;
  for (int k0 = 0; k0 < Tsz; k0 += 16){
    #pragma unroll
    for (int i = 0; i < 4; ++i){
      const int k = kq*4 + i;
      Al[k][lane] = xb[(size_t)(k0+k)*Nsz + n0 + lane];
      Bl[k][lane] = Ue[(size_t)(k0+k)*Tsz + u0 + lane];
    }
    __syncthreads();
    #pragma unroll
    for (int kk = 0; kk < 16; ++kk){
      const float4 a = *(const float4*)&Al[kk][ty*4];
      const float4 w = *(const float4*)&Bl[kk][tx*4];
      const float av[4] = {a.x,a.y,a.z,a.w};
      const float wv[4] = {w.x,w.y,w.z,w.w};
      #pragma unroll
      for (int i=0;i<4;++i)
        #pragma unroll
        for (int j=0;j<4;++j)
          acc[i][j] = fmaf(av[i], wv[j], acc[i][j]);
    }
    __syncthreads();
  }
  float* Qb = Q + (size_t)b * Nsz * Tsz;
  #pragma unroll
  for (int i=0;i<4;++i){
    float4 v;
    v.x = __expf(2.0f*acc[i][0]);
    v.y = __expf(2.0f*acc[i][1]);
    v.z = __expf(2.0f*acc[i][2]);
    v.w = __expf(2.0f*acc[i][3]);
    *(float4*)&Qb[(size_t)(n0 + ty*4 + i)*Tsz + u0 + tx*4] = v;
  }
}

// ---------------------------------------------------------------------------
// K2: persistent LSTM scan, v4 (unchanged from round 4 — zero cache-maintenance
// sync; sc0 sc1 write-through HS, relaxed flags).
// ---------------------------------------------------------------------------
__global__ __launch_bounds__(256, 1) void k_scan(const float* __restrict__ x,
                                                 const float* __restrict__ Wk,
                                                 const float* __restrict__ Wr,
                                                 const float* __restrict__ bias,
                                                 const float* __restrict__ s_in,
                                                 unsigned short* __restrict__ HS,
                                                 int* __restrict__ ctr){
  const int bgq = blockIdx.x & 31;    // batch group 0..31 (16 batches)
  const int ug  = blockIdx.x >> 5;    // unit group 0..3 (64 units)
  const int b0  = bgq * 16;
  const int u0  = ug * 64;
  const int tid  = threadIdx.x;
  const int w    = tid >> 6;          // wave 0..3 -> units u0+16w..
  const int lane = tid & 63;
  const int nl   = lane & 15;
  const int kq   = lane >> 4;

  __shared__ unsigned short Xa[4*16*32];   // x_t chunks (k=0..127),   4 KB
  __shared__ unsigned short Ha[8*16*32];   // h_t chunks (k=128..383), 8 KB

  const int ucol = u0 + (w<<4) + nl;       // this lane's unit column

  // ---- preload W fragments (bf16) into registers: 12 chunks x 4 gates ----
  short8 wf[12][4];
  #pragma unroll
  for (int c = 0; c < 12; ++c){
    #pragma unroll
    for (int g = 0; g < 4; ++g){
      const int jcol = g*Msz + ucol;
      short8 f;
      #pragma unroll
      for (int j = 0; j < 8; ++j){
        const int k = c*32 + kq*8 + j;
        const float wv = (k < Nsz) ? Wk[(size_t)k*(4*Msz) + jcol]
                                   : Wr[(size_t)(k - Nsz)*(4*Msz) + jcol];
        f[j] = (short)bf16r(wv);
      }
      wf[c][g] = f;
    }
  }

  // ---- per-lane state: 4 batch rows x 1 unit ----
  const int r0 = kq*4;                     // first of 4 batch rows (C layout)
  float bi[4];
  #pragma unroll
  for (int g = 0; g < 4; ++g) bi[g] = bias[g*Msz + ucol];
  float s_reg[4];
  #pragma unroll
  for (int r = 0; r < 4; ++r)
    s_reg[r] = s_in[(size_t)(b0 + r0 + r)*Msz + ucol];

  // staging indices (256 threads cover 16 rows x full width)
  const int srow = tid >> 4;               // 0..15
  const int sx_n = (tid & 15) * 8;         // x col base (8 fp32)
  const int sh_m = (tid & 15) * 16;        // h col base (16 units)
  const int arow = nl*32 + kq*8;           // A-fragment LDS offset (shorts)

  #pragma unroll 1
  for (int t = 0; t < Tsz - 1; ++t){
    // ---- stage x_t (no dependence on the group barrier) ----
    {
      const float* xp = x + ((size_t)(b0+srow)*Tsz + t)*Nsz + sx_n;
      const float4 v0 = *(const float4*)(xp);
      const float4 v1 = *(const float4*)(xp + 4);
      ushort4 o0, o1;
      o0.x = bf16r(v0.x); o0.y = bf16r(v0.y); o0.z = bf16r(v0.z); o0.w = bf16r(v0.w);
      o1.x = bf16r(v1.x); o1.y = bf16r(v1.y); o1.z = bf16r(v1.z); o1.w = bf16r(v1.w);
      const int base = (sx_n>>5)*512 + srow*32 + (sx_n & 31);
      *(ushort4*)&Xa[base]     = o0;
      *(ushort4*)&Xa[base + 4] = o1;
    }
    __syncthreads();   // Xa ready

    // ---- x_t @ Wk : chunks 0..3 (overlaps producers still finishing h_t) ----
    f32x4 acc0 = {0.f,0.f,0.f,0.f}, acc1 = {0.f,0.f,0.f,0.f};
    f32x4 acc2 = {0.f,0.f,0.f,0.f}, acc3 = {0.f,0.f,0.f,0.f};
    #pragma unroll
    for (int c = 0; c < 4; ++c){
      const short8 af = *(const short8*)&Xa[c*512 + arow];
      acc0 = __builtin_amdgcn_mfma_f32_16x16x32_bf16(af, wf[c][0], acc0, 0, 0, 0);
      acc1 = __builtin_amdgcn_mfma_f32_16x16x32_bf16(af, wf[c][1], acc1, 0, 0, 0);
      acc2 = __builtin_amdgcn_mfma_f32_16x16x32_bf16(af, wf[c][2], acc2, 0, 0, 0);
      acc3 = __builtin_amdgcn_mfma_f32_16x16x32_bf16(af, wf[c][3], acc3, 0, 0, 0);
    }

    // ---- wait for h_t: tid0 relaxed spin (no cache ops), then barrier ----
    if (t > 0){
      if (tid == 0){
        int* cp = &ctr[(t-1)*32 + bgq];
        while (__hip_atomic_load(cp, __ATOMIC_RELAXED, __HIP_MEMORY_SCOPE_AGENT) < 4)
          __builtin_amdgcn_s_sleep(1);
      }
      __syncthreads();
    }

    // ---- stage h_t: sc0 sc1 loads (MALL-coherent), extract h (low16) ----
    {
      const unsigned* hp = (const unsigned*)(HS + ((size_t)t*Bsz + b0 + srow)*512) + sh_m;
      uint4 a0, a1, a2, a3;
      asm volatile(
        "global_load_dwordx4 %0, %4, off sc0 sc1\n\t"
        "global_load_dwordx4 %1, %4, off offset:16 sc0 sc1\n\t"
        "global_load_dwordx4 %2, %4, off offset:32 sc0 sc1\n\t"
        "global_load_dwordx4 %3, %4, off offset:48 sc0 sc1\n\t"
        "s_waitcnt vmcnt(0)"
        : "=&v"(a0), "=&v"(a1), "=&v"(a2), "=&v"(a3)
        : "v"(hp)
        : "memory");
      ushort4 h0, h1, h2, h3;
      h0.x=(unsigned short)a0.x; h0.y=(unsigned short)a0.y; h0.z=(unsigned short)a0.z; h0.w=(unsigned short)a0.w;
      h1.x=(unsigned short)a1.x; h1.y=(unsigned short)a1.y; h1.z=(unsigned short)a1.z; h1.w=(unsigned short)a1.w;
      h2.x=(unsigned short)a2.x; h2.y=(unsigned short)a2.y; h2.z=(unsigned short)a2.z; h2.w=(unsigned short)a2.w;
      h3.x=(unsigned short)a3.x; h3.y=(unsigned short)a3.y; h3.z=(unsigned short)a3.z; h3.w=(unsigned short)a3.w;
      const int base = (sh_m>>5)*512 + srow*32 + (sh_m & 31);
      *(ushort4*)&Ha[base +  0] = h0;
      *(ushort4*)&Ha[base +  4] = h1;
      *(ushort4*)&Ha[base +  8] = h2;
      *(ushort4*)&Ha[base + 12] = h3;
    }
    __syncthreads();   // Ha ready

    // ---- h_t @ Wr : chunks 4..11 ----
    #pragma unroll
    for (int c = 0; c < 8; ++c){
      const short8 af = *(const short8*)&Ha[c*512 + arow];
      acc0 = __builtin_amdgcn_mfma_f32_16x16x32_bf16(af, wf[c+4][0], acc0, 0, 0, 0);
      acc1 = __builtin_amdgcn_mfma_f32_16x16x32_bf16(af, wf[c+4][1], acc1, 0, 0, 0);
      acc2 = __builtin_amdgcn_mfma_f32_16x16x32_bf16(af, wf[c+4][2], acc2, 0, 0, 0);
      acc3 = __builtin_amdgcn_mfma_f32_16x16x32_bf16(af, wf[c+4][3], acc3, 0, 0, 0);
    }

    // ---- gate update; pack (h,s) per unit; sc0 sc1 write-through stores ----
    {
      unsigned hv[4];
      #pragma unroll
      for (int r = 0; r < 4; ++r){
        const float ig = sigmoid_fast(acc0[r] + bi[0]);
        const float fg = sigmoid_fast(acc1[r] + bi[1]);
        const float gg = tanh_fast  (acc2[r] + bi[2]);
        const float og = sigmoid_fast(acc3[r] + bi[3]);
        const float s1 = fmaf(fg, s_reg[r], ig * gg);
        s_reg[r] = s1;
        const float hn = og * tanh_fast(s1);
        hv[r] = (unsigned)bf16r(hn) | ((unsigned)bf16r(s1) << 16);
      }
      unsigned* gp = (unsigned*)(HS + ((size_t)(t+1)*Bsz + b0 + r0)*512) + ucol;
      asm volatile(
        "global_store_dword %0, %1, off sc0 sc1\n\t"
        "global_store_dword %0, %2, off offset:1024 sc0 sc1\n\t"
        "global_store_dword %0, %3, off offset:2048 sc0 sc1\n\t"
        "global_store_dword %0, %4, off offset:3072 sc0 sc1\n\t"
        "s_waitcnt vmcnt(0)"
        :: "v"(gp), "v"(hv[0]), "v"(hv[1]), "v"(hv[2]), "v"(hv[3])
        : "memory");
    }

    // ---- publish: stores already at MALL -> relaxed flag add ----
    __syncthreads();
    if (tid == 0)
      __hip_atomic_fetch_add(&ctr[t*32 + bgq], 1, __ATOMIC_RELAXED,
                             __HIP_MEMORY_SCOPE_AGENT);
  }
}

// ---------------------------------------------------------------------------
// K3: attention v3 — MFMA r1 GEMM + 4-blocks/CU occupancy.
// Phase 1: packed HS row -> Al bf16 [16][512] (XOR-swizzled, 16KB); r1 via
//   mfma_16x16x32_bf16 with We converted on the fly to bf16 + bf16-residual
//   (two accumulating MFMAs ~= fp32 We); Pl = exp(2*r1).
// Phase 2: e-loop, u-chunks of 32 (Qu [128][36] aliases Al region).
// LDS: Pl 16.6K | union{Al 16K, Qu 18.4K} | vel 1K = 36.1KB -> 4 blocks/CU.
// ---------------------------------------------------------------------------
__global__ __launch_bounds__(256, 4) void k_attn(const unsigned short* __restrict__ HS,
                                              const float* __restrict__ Q,
                                              const float* __restrict__ We,
                                              const float* __restrict__ ve,
                                              const float* __restrict__ x,
                                              float* __restrict__ out){
  const unsigned wgid = blockIdx.x + (blockIdx.y << 9);
  const unsigned l    = ((wgid & 7u) << 10) + (wgid >> 3);
  const int b  = (int)(l >> 4);
  const int t0 = (int)(l & 15u) << 4;

  __shared__ __align__(16) char smem[36096];
  float* Pl  = (float*)smem;               // [16][260] fp32
  char*  Ab  = smem + 16640;               // Al: [16][512] bf16 swizzled (phase 1)
  float* Qu  = (float*)(smem + 16640);     // [128][36] fp32 (phase 2, aliases Al)
  float* vel = (float*)(smem + 35072);     // [256]

  const int tid = threadIdx.x;
  vel[tid] = ve[tid];

  // ---- stage packed HS -> Al bf16 [16][512], XOR-swizzle ((row&7)<<4) ----
  {
    const int row = tid >> 4;
    const int seg = tid & 15;
    const uint4* src = (const uint4*)((const unsigned*)(HS + ((size_t)(t0 + row)*Bsz + b)*512) + seg*16);
    const uint4 q0 = src[0], q1 = src[1], q2 = src[2], q3 = src[3];
    ushort8v h0 = {(unsigned short)q0.x,(unsigned short)q0.y,(unsigned short)q0.z,(unsigned short)q0.w,
                   (unsigned short)q1.x,(unsigned short)q1.y,(unsigned short)q1.z,(unsigned short)q1.w};
    ushort8v h1 = {(unsigned short)q2.x,(unsigned short)q2.y,(unsigned short)q2.z,(unsigned short)q2.w,
                   (unsigned short)q3.x,(unsigned short)q3.y,(unsigned short)q3.z,(unsigned short)q3.w};
    ushort8v s0 = {(unsigned short)(q0.x>>16),(unsigned short)(q0.y>>16),(unsigned short)(q0.z>>16),(unsigned short)(q0.w>>16),
                   (unsigned short)(q1.x>>16),(unsigned short)(q1.y>>16),(unsigned short)(q1.z>>16),(unsigned short)(q1.w>>16)};
    ushort8v s1 = {(unsigned short)(q2.x>>16),(unsigned short)(q2.y>>16),(unsigned short)(q2.z>>16),(unsigned short)(q2.w>>16),
                   (unsigned short)(q3.x>>16),(unsigned short)(q3.y>>16),(unsigned short)(q3.z>>16),(unsigned short)(q3.w>>16)};
    const int sw = (row & 7) << 4;
    const int hb = row*1024 + seg*32;      // logical byte of h-part
    *(ushort8v*)(Ab + ((hb      ) ^ sw)) = h0;
    *(ushort8v*)(Ab + ((hb + 16 ) ^ sw)) = h1;
    *(ushort8v*)(Ab + ((hb + 512) ^ sw)) = s0;
    *(ushort8v*)(Ab + ((hb + 528) ^ sw)) = s1;
  }
  __syncthreads();

  // ---- r1 via MFMA: wave w owns u in [w*64, w*64+64) ----
  {
    const int lane = tid & 63;
    const int w    = tid >> 6;
    const int nl16 = lane & 15;            // = A row (t), = B col (u_local)
    const int kq   = lane >> 4;
    f32x4 acc[4];
    #pragma unroll
    for (int nt = 0; nt < 4; ++nt) acc[nt] = (f32x4){0.f,0.f,0.f,0.f};
    const int aswz = (nl16 & 7) << 4;
    #pragma unroll 1
    for (int kc = 0; kc < 16; ++kc){
      const short8 af = *(const short8*)(Ab + ((nl16*1024 + kc*64 + kq*16) ^ aswz));
      #pragma unroll
      for (int nt = 0; nt < 4; ++nt){
        const float* wp = We + (size_t)(kc*32 + kq*8)*256 + w*64 + nt*16 + nl16;
        float v0 = wp[0],    v1 = wp[256],  v2 = wp[512],  v3 = wp[768];
        float v4 = wp[1024], v5 = wp[1280], v6 = wp[1536], v7 = wp[1792];
        short8 b1, b2;
        const float vv[8] = {v0,v1,v2,v3,v4,v5,v6,v7};
        #pragma unroll
        for (int j = 0; j < 8; ++j){
          const unsigned short w1 = bf16r(vv[j]);
          b1[j] = (short)w1;
          const float res = vv[j] - __uint_as_float((unsigned)w1 << 16);
          b2[j] = (short)bf16r(res);
        }
        acc[nt] = __builtin_amdgcn_mfma_f32_16x16x32_bf16(af, b1, acc[nt], 0, 0, 0);
        acc[nt] = __builtin_amdgcn_mfma_f32_16x16x32_bf16(af, b2, acc[nt], 0, 0, 0);
      }
    }
    // D layout: col = lane&15 (u_local), row = (lane>>4)*4 + r (t)
    #pragma unroll
    for (int nt = 0; nt < 4; ++nt)
      #pragma unroll
      for (int r = 0; r < 4; ++r)
        Pl[(kq*4 + r)*260 + w*64 + nt*16 + nl16] = __expf(2.0f*acc[nt][r]);
  }

  // ---- e-loop: thread tile = t rows {2tt, 2tt+1} x n cols {tn + 32r} ----
  const int tt = tid >> 5;                 // 0..7
  const int tn = tid & 31;                 // 0..31
  float acc[2][4] = {};
  const float* Qb = Q + (size_t)b * Nsz * Tsz;

  for (int u0 = 0; u0 < Tsz; u0 += 32){
    __syncthreads();                       // prior readers of region done
    #pragma unroll
    for (int i2 = 0; i2 < 4; ++i2){
      const int seg = i2*256 + tid;        // 0..1023
      const int row = seg >> 3;            // 0..127
      const int q   = seg & 7;             // 0..7
      *(float4*)&Qu[row*36 + q*4] = *(const float4*)&Qb[row*256 + u0 + q*4];
    }
    __syncthreads();
    #pragma unroll
    for (int us = 0; us < 8; ++us){
      const int uu = u0 + us*4;
      const float4 ve4 = *(const float4*)&vel[uu];
      const float4 p0  = *(const float4*)&Pl[(2*tt+0)*260 + uu];
      const float4 p1  = *(const float4*)&Pl[(2*tt+1)*260 + uu];
      #pragma unroll
      for (int r = 0; r < 4; ++r){
        const float4 qv = *(const float4*)&Qu[(tn + 32*r)*36 + us*4];
        acc[0][r] = fmaf(ve4.x, rcp_fast(fmaf(p0.x, qv.x, 1.0f)), acc[0][r]);
        acc[0][r] = fmaf(ve4.y, rcp_fast(fmaf(p0.y, qv.y, 1.0f)), acc[0][r]);
        acc[0][r] = fmaf(ve4.z, rcp_fast(fmaf(p0.z, qv.z, 1.0f)), acc[0][r]);
        acc[0][r] = fmaf(ve4.w, rcp_fast(fmaf(p0.w, qv.w, 1.0f)), acc[0][r]);
        acc[1][r] = fmaf(ve4.x, rcp_fast(fmaf(p1.x, qv.x, 1.0f)), acc[1][r]);
        acc[1][r] = fmaf(ve4.y, rcp_fast(fmaf(p1.y, qv.y, 1.0f)), acc[1][r]);
        acc[1][r] = fmaf(ve4.z, rcp_fast(fmaf(p1.z, qv.z, 1.0f)), acc[1][r]);
        acc[1][r] = fmaf(ve4.w, rcp_fast(fmaf(p1.w, qv.w, 1.0f)), acc[1][r]);
      }
    }
  }

  // ---- softmax in registers (row t in one 32-lane group) ----
  float ex[2][4];
  float m0 = -3.0e38f, m1 = -3.0e38f;
  #pragma unroll
  for (int r = 0; r < 4; ++r){
    ex[0][r] = -2.0f * acc[0][r];
    ex[1][r] = -2.0f * acc[1][r];
    m0 = fmaxf(m0, ex[0][r]);
    m1 = fmaxf(m1, ex[1][r]);
  }
  #pragma unroll
  for (int mk = 16; mk >= 1; mk >>= 1){
    m0 = fmaxf(m0, __shfl_xor(m0, mk, 64));
    m1 = fmaxf(m1, __shfl_xor(m1, mk, 64));
  }
  float s0 = 0.0f, s1 = 0.0f;
  #pragma unroll
  for (int r = 0; r < 4; ++r){
    const float p0 = __expf(ex[0][r] - m0);
    const float p1 = __expf(ex[1][r] - m1);
    ex[0][r] = p0; ex[1][r] = p1;
    s0 += p0; s1 += p1;
  }
  #pragma unroll
  for (int mk = 16; mk >= 1; mk >>= 1){
    s0 += __shfl_xor(s0, mk, 64);
    s1 += __shfl_xor(s1, mk, 64);
  }
  const float inv0 = rcp_fast(s0);
  const float inv1 = rcp_fast(s1);

  #pragma unroll
  for (int r = 0; r < 4; ++r){
    const size_t i0 = ((size_t)b*Tsz + t0 + 2*tt + 0)*Nsz + tn + 32*r;
    const size_t i1 = ((size_t)b*Tsz + t0 + 2*tt + 1)*Nsz + tn + 32*r;
    out[i0] = ex[0][r] * inv0 * x[i0];
    out[i1] = ex[1][r] * inv1 * x[i1];
  }
}

// ---------------------------------------------------------------------------
extern "C" void kernel_launch(void* const* d_in, const int* in_sizes, int n_in,
                              void* d_out, int out_size, void* d_ws, size_t ws_size,
                              hipStream_t stream){
  const float* x    = (const float*)d_in[0];
  const float* s_in = (const float*)d_in[1];
  const float* h_in = (const float*)d_in[2];
  const float* We   = (const float*)d_in[3];
  const float* Ue   = (const float*)d_in[4];
  const float* ve   = (const float*)d_in[5];
  const float* Wk   = (const float*)d_in[6];
  const float* Wr   = (const float*)d_in[7];
  const float* bias = (const float*)d_in[8];
  float* out = (float*)d_out;

  // ws layout (~201.4 MB): Q fp32 67MB | HS 134MB | ctr 32KB
  float* Q = (float*)d_ws;
  unsigned short* HS = (unsigned short*)(Q + (size_t)Bsz*Nsz*Tsz);
  int* ctr = (int*)(HS + (size_t)Tsz*Bsz*512);

  k_init<<<(Bsz*Msz)/256, 256, 0, stream>>>(h_in, s_in, HS, ctr);
  k_r2exp<<<dim3(Bsz, 8), 256, 0, stream>>>(x, Ue, Q);
  k_scan<<<128, 256, 0, stream>>>(x, Wk, Wr, bias, s_in, HS, ctr);
  k_attn<<<dim3(Bsz, Tsz/16), 256, 0, stream>>>(HS, Q, We, ve, x, out);
}